// Round 14
// baseline (309.104 us; speedup 1.0000x reference)
//
#include <hip/hip_runtime.h>
#include <math.h>

#define HH 128
#define WW 128
#define HWSZ 16384

typedef __attribute__((ext_vector_type(8))) short short8;
typedef __attribute__((ext_vector_type(4))) float f32x4;
typedef __attribute__((ext_vector_type(2))) float f32x2;
typedef unsigned short ushort;

__device__ __forceinline__ ushort f2bf(float f) {
    unsigned int u = __float_as_uint(f);
    unsigned int r = u + 0x7fffu + ((u >> 16) & 1u);
    return (ushort)(r >> 16);
}
// unpack 2 packed bf16 (one dword) to float2: .x = low half, .y = high half
__device__ __forceinline__ f32x2 unpk(unsigned u) {
    return (f32x2){__uint_as_float(u << 16),
                   __uint_as_float(u & 0xffff0000u)};
}

// ---- merged weight prep: wpad1 | wpad2 | woff1 | woff2 in one launch ----
__global__ __launch_bounds__(256) void prep_weights(
    const float* __restrict__ w1, const float* __restrict__ w2,
    const float* __restrict__ w_off1, const float* __restrict__ w_mod1,
    const float* __restrict__ w_off2, const float* __restrict__ w_mod2,
    ushort* __restrict__ Wt1, ushort* __restrict__ Wt2,
    ushort* __restrict__ Wo1, ushort* __restrict__ Wo2) {
    int bid = blockIdx.x, tid = threadIdx.x;
    if (bid < 336) {
        int i = bid * 256 + tid;
        int o = i / 672, kq = i % 672;
        int k = kq / 72, c = kq % 72;
        float v = (k < 9 && c < 64) ? w1[(o * 64 + c) * 9 + k] : 0.f;
        Wt1[i] = f2bf(v);
    } else if (bid < 960) {
        int i = (bid - 336) * 256 + tid;
        int o = i / 1248, kq = i % 1248;
        int k = kq / 136, c = kq % 136;
        float v = (k < 9 && c < 128) ? w2[(o * 128 + c) * 9 + k] : 0.f;
        Wt2[i] = f2bf(v);
    } else if (bid < 1032) {
        int i = (bid - 960) * 256 + tid;  // < 32*576
        int o = i / 576, kap = i % 576;
        int k = kap / 64, c = kap % 64;
        float v = 0.f;
        if (o < 18) v = w_off1[(o * 64 + c) * 9 + k];
        else if (o < 27) v = w_mod1[((o - 18) * 64 + c) * 9 + k];
        Wo1[i] = f2bf(v);
    } else {
        int i = (bid - 1032) * 256 + tid;  // < 32*1152
        int o = i / 1152, kap = i % 1152;
        int k = kap / 128, c = kap % 128;
        float v = 0.f;
        if (o < 18) v = w_off2[(o * 128 + c) * 9 + k];
        else if (o < 27) v = w_mod2[((o - 18) * 128 + c) * 9 + k];
        Wo2[i] = f2bf(v);
    }
}

// ---- NCHW fp32 -> NHWC bf16 converter (tiled transpose) ----
template <int C>
__global__ __launch_bounds__(256) void nhwc_cvt(const float* __restrict__ xin,
                                                unsigned* __restrict__ xout) {
    __shared__ float tile[64][C + 1];
    const int m0 = blockIdx.x * 64;
    const int b = m0 >> 14;
    const int hw0 = m0 & 16383;
    const int t = threadIdx.x;
    const int pr = t & 63, cr = t >> 6;
#pragma unroll
    for (int it = 0; it < C / 4; ++it) {
        int c = it * 4 + cr;
        tile[pr][c] = xin[(((size_t)(b * C + c)) << 14) + hw0 + pr];
    }
    __syncthreads();
    constexpr int CH = C / 2;
#pragma unroll
    for (int it = 0; it < 64 * CH / 256; ++it) {
        int slot = it * 256 + t;
        int p = slot / CH, cc = slot % CH;
        unsigned lo = f2bf(tile[p][2 * cc]);
        unsigned hi = f2bf(tile[p][2 * cc + 1]);
        xout[(size_t)(m0 + p) * CH + cc] = lo | (hi << 16);
    }
}

// ---- fused bn finalize(from praw replicas) + norm/relu + NHWC bf16 cvt ----
template <int C>
__global__ __launch_bounds__(256) void bn_apply_cvt(
    const float* __restrict__ xin, const float* __restrict__ praw,
    unsigned* __restrict__ xout) {
    __shared__ float tile[64][C + 1];
    __shared__ float lstats[256];
    const int t = threadIdx.x;
    if (t < 128) {
        float s = 0.f, q = 0.f;
#pragma unroll
        for (int r = 0; r < 8; ++r) {
            s += praw[r * 256 + t];
            q += praw[r * 256 + 128 + t];
        }
        float mean = s / 65536.f;
        float var = q / 65536.f - mean * mean;
        lstats[t] = mean;
        lstats[128 + t] = rsqrtf(var + 1e-5f);
    }
    __syncthreads();
    const int m0 = blockIdx.x * 64;
    const int b = m0 >> 14;
    const int hw0 = m0 & 16383;
    const int pr = t & 63, cr = t >> 6;
#pragma unroll
    for (int it = 0; it < C / 4; ++it) {
        int c = it * 4 + cr;
        float v = xin[(((size_t)(b * C + c)) << 14) + hw0 + pr];
        tile[pr][c] = fmaxf(0.f, (v - lstats[c]) * lstats[C + c]);
    }
    __syncthreads();
    constexpr int CH = C / 2;
#pragma unroll
    for (int it = 0; it < 64 * CH / 256; ++it) {
        int slot = it * 256 + t;
        int p = slot / CH, cc = slot % CH;
        unsigned lo = f2bf(tile[p][2 * cc]);
        unsigned hi = f2bf(tile[p][2 * cc + 1]);
        xout[(size_t)(m0 + p) * CH + cc] = lo | (hi << 16);
    }
}

// ---- offset/mod conv: NHWC-bf16 direct A-fragment MFMA GEMM ----
// also zeroes the bn praw replicas (blocks 0..7) for the following deform.
template <int C>
__global__ __launch_bounds__(256) void offmod_nhwc(
    const ushort* __restrict__ xh, const ushort* __restrict__ wt,
    const float* __restrict__ b_off, const float* __restrict__ b_mod,
    float* __restrict__ dyb, float* __restrict__ dxb, float* __restrict__ mob,
    float* __restrict__ praw) {
    constexpr int K = C * 9;
    if (blockIdx.x < 8) praw[blockIdx.x * 256 + threadIdx.x] = 0.f;
    const int m0 = blockIdx.x * 64;
    const int b = m0 >> 14;
    const int hw0 = m0 & 16383;
    const int h = hw0 >> 7;
    const int w0 = hw0 & 127;
    const int tid = threadIdx.x;
    const int lane = tid & 63, wv = tid >> 6;
    const int n16 = lane & 15, quad = lane >> 4;
    const int p = wv * 16 + n16;
    const int w = w0 + p;

    int tbase[9];
    bool tval[9];
#pragma unroll
    for (int k = 0; k < 9; ++k) {
        int yy = h + k / 3 - 1, xx = w + k % 3 - 1;
        tval[k] = ((unsigned)yy < 128u) && ((unsigned)xx < 128u);
        int cy = min(max(yy, 0), 127), cx = min(max(xx, 0), 127);
        tbase[k] = ((b << 14) + (cy << 7) + cx) * C + quad * 8;
    }

    f32x4 acc[2];
    acc[0] = (f32x4){0.f, 0.f, 0.f, 0.f};
    acc[1] = (f32x4){0.f, 0.f, 0.f, 0.f};

    const ushort* b0p = wt + (size_t)n16 * K + quad * 8;
    const ushort* b1p = wt + (size_t)(16 + n16) * K + quad * 8;

#pragma unroll
    for (int s = 0; s < K / 32; ++s) {
        const int k = (s * 32) / C;
        const int c0 = (s * 32) % C;
        short8 a = (short8){0, 0, 0, 0, 0, 0, 0, 0};
        if (tval[k]) a = *(const short8*)(xh + (size_t)tbase[k] + c0);
        const short8 bv0 = *(const short8*)(b0p + s * 32);
        const short8 bv1 = *(const short8*)(b1p + s * 32);
        acc[0] = __builtin_amdgcn_mfma_f32_16x16x32_bf16(a, bv0, acc[0], 0, 0, 0);
        acc[1] = __builtin_amdgcn_mfma_f32_16x16x32_bf16(a, bv1, acc[1], 0, 0, 0);
    }

    __shared__ float sm[32 * 65];
#pragma unroll
    for (int nt = 0; nt < 2; ++nt) {
        int n = nt * 16 + n16;
        int pb = wv * 16 + quad * 4;
#pragma unroll
        for (int r = 0; r < 4; ++r) sm[n * 65 + pb + r] = acc[nt][r];
    }
    __syncthreads();
    {
        int n = tid >> 3, i8 = tid & 7;
        if (n < 27) {
            const float* sp = sm + n * 65 + i8 * 8;
            int px = hw0 + i8 * 8;
            if (n < 18) {
                int k = n >> 1;
                float bias = b_off[n];
                float* dst =
                    ((n & 1) ? dxb : dyb) + (((size_t)(b * 9 + k)) << 14) + px;
#pragma unroll
                for (int j = 0; j < 8; j += 4) {
                    float4 v = make_float4(sp[j] + bias, sp[j + 1] + bias,
                                           sp[j + 2] + bias, sp[j + 3] + bias);
                    *(float4*)(dst + j) = v;
                }
            } else {
                float bias = b_mod[n - 18];
                float* dst = mob + (((size_t)(b * 9 + (n - 18))) << 14) + px;
#pragma unroll
                for (int j = 0; j < 8; j += 4) {
                    float4 v;
                    v.x = 2.f / (1.f + expf(-(sp[j] + bias)));
                    v.y = 2.f / (1.f + expf(-(sp[j + 1] + bias)));
                    v.z = 2.f / (1.f + expf(-(sp[j + 2] + bias)));
                    v.w = 2.f / (1.f + expf(-(sp[j + 3] + bias)));
                    *(float4*)(dst + j) = v;
                }
            }
        }
    }
}

// ---- deformable conv v5: PIX=64, 512 threads / 8 waves ----
// wave = (pixhalf = wv>>2, colslice = wv&3): 32px x 32oc tile each; twin
// waves sharing a colslice dedup B reads in L1; blocks halve -> B L2
// traffic halves. Per-thread regs/loads identical to green R10 (NIT<=2).
// K-chunked (per-tap) double-buffered; epilogue fuses bn partial stats.
template <int C>
__global__ __launch_bounds__(512) void deform_mfma5(
    const ushort* __restrict__ xh, const float* __restrict__ dyb,
    const float* __restrict__ dxb, const float* __restrict__ mob,
    const ushort* __restrict__ wt, float* __restrict__ out,
    float* __restrict__ praw) {
    constexpr int PIX = 64;
    constexpr int AST = C + 8;
    constexpr int CPW = C + 8;
    constexpr int KP = ((9 * CPW + 31) / 32) * 32;
    constexpr int NCC = C / 8;
    constexpr int NIT = PIX * NCC / 512;  // 1 (C=64) or 2 (C=128)
    constexpr int ABUF = PIX * AST;

    __shared__ __align__(16) char smem_raw[2 * ABUF * 2 + PIX * 9 * 32];
    ushort* abuf0 = (ushort*)smem_raw;
    ushort* abuf1 = abuf0 + ABUF;
    int* tb = (int*)(abuf0 + 2 * ABUF);
    float* tw = (float*)(tb + PIX * 9 * 4);

    const int m0 = blockIdx.x * PIX;
    const int b = m0 >> 14;
    const int hw0 = m0 & 16383;
    const int h = hw0 >> 7, w0 = hw0 & 127;
    const int tid = threadIdx.x;

    for (int r = tid; r < PIX * 9; r += 512) {
        int p = r & (PIX - 1), k = r / PIX;
        int oi = ((b * 9 + k) << 14) + hw0 + p;
        float py = (float)(h + k / 3 - 1) + dyb[oi];
        float px = (float)(w0 + p + k % 3 - 1) + dxb[oi];
        float mv = mob[oi];
        float y0f = floorf(py), x0f = floorf(px);
        float wy = py - y0f, wx = px - x0f;
        int y0 = (int)y0f, x0 = (int)x0f;
        int y1 = y0 + 1, x1 = x0 + 1;
        float f00 = (1.f - wy) * (1.f - wx) *
                    (((unsigned)y0 < 128u && (unsigned)x0 < 128u) ? mv : 0.f);
        float f01 = (1.f - wy) * wx *
                    (((unsigned)y0 < 128u && (unsigned)x1 < 128u) ? mv : 0.f);
        float f10 = wy * (1.f - wx) *
                    (((unsigned)y1 < 128u && (unsigned)x0 < 128u) ? mv : 0.f);
        float f11 = wy * wx *
                    (((unsigned)y1 < 128u && (unsigned)x1 < 128u) ? mv : 0.f);
        int cy0 = min(max(y0, 0), 127), cy1 = min(max(y1, 0), 127);
        int cx0 = min(max(x0, 0), 127), cx1 = min(max(x1, 0), 127);
        int bpx = b << 14;
        int s = (p * 9 + k) * 4;
        tb[s + 0] = (bpx + (cy0 << 7) + cx0) * C;
        tb[s + 1] = (bpx + (cy0 << 7) + cx1) * C;
        tb[s + 2] = (bpx + (cy1 << 7) + cx0) * C;
        tb[s + 3] = (bpx + (cy1 << 7) + cx1) * C;
        tw[s + 0] = f00;
        tw[s + 1] = f01;
        tw[s + 2] = f10;
        tw[s + 3] = f11;
    }
    __syncthreads();

    auto issue_loads = [&](int kc, uint4 (&q)[NIT][4], float4 (&fw)[NIT]) {
#pragma unroll
        for (int it = 0; it < NIT; ++it) {
            int e = it * 512 + tid;
            int p = e / NCC, cc = e % NCC;
            int s = (p * 9 + kc) * 4;
            int4 bi = *(const int4*)&tb[s];
            fw[it] = *(const float4*)&tw[s];
            q[it][0] = *(const uint4*)(xh + (size_t)bi.x + cc * 8);
            q[it][1] = *(const uint4*)(xh + (size_t)bi.y + cc * 8);
            q[it][2] = *(const uint4*)(xh + (size_t)bi.z + cc * 8);
            q[it][3] = *(const uint4*)(xh + (size_t)bi.w + cc * 8);
        }
    };
    auto interp_write = [&](ushort* dst, uint4 (&q)[NIT][4], float4 (&fw)[NIT]) {
#pragma unroll
        for (int it = 0; it < NIT; ++it) {
            int e = it * 512 + tid;
            int p = e / NCC, cc = e % NCC;
            unsigned a0[4] = {q[it][0].x, q[it][0].y, q[it][0].z, q[it][0].w};
            unsigned a1[4] = {q[it][1].x, q[it][1].y, q[it][1].z, q[it][1].w};
            unsigned a2[4] = {q[it][2].x, q[it][2].y, q[it][2].z, q[it][2].w};
            unsigned a3[4] = {q[it][3].x, q[it][3].y, q[it][3].z, q[it][3].w};
            unsigned ov[4];
#pragma unroll
            for (int dw = 0; dw < 4; ++dw) {
                f32x2 v = unpk(a0[dw]) * fw[it].x;
                v += unpk(a1[dw]) * fw[it].y;
                v += unpk(a2[dw]) * fw[it].z;
                v += unpk(a3[dw]) * fw[it].w;
                ov[dw] = (unsigned)f2bf(v.x) | ((unsigned)f2bf(v.y) << 16);
            }
            *(uint4*)&dst[p * AST + cc * 8] = uint4{ov[0], ov[1], ov[2], ov[3]};
        }
    };

    {
        uint4 q[NIT][4];
        float4 fw[NIT];
        issue_loads(0, q, fw);
        interp_write(abuf0, q, fw);
    }
    __syncthreads();

    const int lane = tid & 63, wv = tid >> 6;
    const int n16 = lane & 15, quad = lane >> 4;
    const int colslice = wv & 3, pixhalf = wv >> 2;

    f32x4 acc[2][2];
#pragma unroll
    for (int mt = 0; mt < 2; ++mt)
#pragma unroll
        for (int nt = 0; nt < 2; ++nt) acc[mt][nt] = (f32x4){0.f, 0.f, 0.f, 0.f};

    const ushort* bbase[2];
#pragma unroll
    for (int nt = 0; nt < 2; ++nt)
        bbase[nt] =
            wt + (size_t)(colslice * 32 + nt * 16 + n16) * KP + quad * 8;

#pragma unroll 1
    for (int kc = 0; kc < 9; ++kc) {
        uint4 q[NIT][4];
        float4 fw[NIT];
        if (kc < 8) issue_loads(kc + 1, q, fw);

        const ushort* ab = (kc & 1) ? abuf1 : abuf0;
#pragma unroll
        for (int s = 0; s < C / 32; ++s) {
            short8 av[2], bv[2];
#pragma unroll
            for (int mt = 0; mt < 2; ++mt)
                av[mt] = *(const short8*)(ab + (pixhalf * 32 + mt * 16 + n16) *
                                                   AST +
                                          s * 32 + quad * 8);
#pragma unroll
            for (int nt = 0; nt < 2; ++nt)
                bv[nt] = *(const short8*)(bbase[nt] + kc * CPW + s * 32);
#pragma unroll
            for (int mt = 0; mt < 2; ++mt)
#pragma unroll
                for (int nt = 0; nt < 2; ++nt)
                    acc[mt][nt] = __builtin_amdgcn_mfma_f32_16x16x32_bf16(
                        av[mt], bv[nt], acc[mt][nt], 0, 0, 0);
        }
        if (kc < 8)
            interp_write((kc & 1) ? abuf0 : abuf1, q, fw);
        __syncthreads();
    }

    // ---- epilogue: transpose via LDS; stores + fused bn partial stats ----
    float* sm = (float*)smem_raw;
    constexpr int SROW = PIX + 1;
#pragma unroll
    for (int mt = 0; mt < 2; ++mt)
#pragma unroll
        for (int nt = 0; nt < 2; ++nt) {
            int o = colslice * 32 + nt * 16 + n16;
            int pb = pixhalf * 32 + mt * 16 + quad * 4;
#pragma unroll
            for (int r = 0; r < 4; ++r) sm[o * SROW + pb + r] = acc[mt][nt][r];
        }
    __syncthreads();
    {
        int o = tid >> 2, qtr = tid & 3;  // 128 channels, 16 px per thread
        const float* sp = sm + o * SROW + qtr * 16;
        float* op = out + (((size_t)(b * 128 + o)) << 14) + hw0 + qtr * 16;
        float s = 0.f, qq = 0.f;
#pragma unroll
        for (int i = 0; i < 16; i += 4) {
            float4 v = make_float4(sp[i], sp[i + 1], sp[i + 2], sp[i + 3]);
            *(float4*)(op + i) = v;
            s += v.x + v.y + v.z + v.w;
            qq += v.x * v.x + v.y * v.y + v.z * v.z + v.w * v.w;
        }
        s += __shfl_down(s, 1, 64);
        qq += __shfl_down(qq, 1, 64);
        s += __shfl_down(s, 2, 64);
        qq += __shfl_down(qq, 2, 64);
        if (qtr == 0) {
            float* pr = praw + (blockIdx.x & 7) * 256;
            atomicAdd(&pr[o], s);
            atomicAdd(&pr[128 + o], qq);
        }
    }
}

// ---- fused bn finalize + bn + relu + 2x2 maxpool ----
__global__ __launch_bounds__(256) void bn_pool(const float* __restrict__ x,
                                               const float* __restrict__ praw,
                                               float* __restrict__ out, int B,
                                               int C) {
    __shared__ float lstats[256];
    if (threadIdx.x < 128) {
        int c = threadIdx.x;
        float s = 0.f, q = 0.f;
#pragma unroll
        for (int r = 0; r < 8; ++r) {
            s += praw[r * 256 + c];
            q += praw[r * 256 + 128 + c];
        }
        float mean = s / 65536.f;
        float var = q / 65536.f - mean * mean;
        lstats[c] = mean;
        lstats[128 + c] = rsqrtf(var + 1e-5f);
    }
    __syncthreads();
    const int Ho = 64, Wo = 64;
    int i = blockIdx.x * blockDim.x + threadIdx.x;
    int total = B * C * Ho * Wo;
    if (i >= total) return;
    int ow = i % Wo;
    int t = i / Wo;
    int oh = t % Ho;
    t /= Ho;
    int c = t % C;
    int b = t / C;
    const float* p = x + ((size_t)(b * C + c)) * HWSZ + (2 * oh) * WW + 2 * ow;
    float m0 = fmaxf(p[0], p[1]);
    float m1 = fmaxf(p[WW], p[WW + 1]);
    float mx = fmaxf(m0, m1);
    out[i] = fmaxf(0.f, (mx - lstats[c]) * lstats[C + c]);
}

extern "C" void kernel_launch(void* const* d_in, const int* in_sizes, int n_in,
                              void* d_out, int out_size, void* d_ws,
                              size_t ws_size, hipStream_t stream) {
    (void)in_sizes;
    (void)n_in;
    (void)out_size;
    (void)ws_size;
    const float* x = (const float*)d_in[0];
    const float* w_off1 = (const float*)d_in[1];
    const float* b_off1 = (const float*)d_in[2];
    const float* w_mod1 = (const float*)d_in[3];
    const float* b_mod1 = (const float*)d_in[4];
    const float* w1 = (const float*)d_in[5];
    const float* w_off2 = (const float*)d_in[6];
    const float* b_off2 = (const float*)d_in[7];
    const float* w_mod2 = (const float*)d_in[8];
    const float* b_mod2 = (const float*)d_in[9];
    const float* w2 = (const float*)d_in[10];
    float* out = (float*)d_out;
    float* ws = (float*)d_ws;

    // KP1 = 672 (C=64, CP=72), KP2 = 1248 (C=128, CP=136)
    ushort* Wt1 = (ushort*)ws;                            // 86016 ush = 43008 f
    ushort* Wt2 = (ushort*)(ws + 43008);                  // 159744 ush = 79872 f
    ushort* Wo1 = (ushort*)(ws + 43008 + 79872);          // need 18432 ush
    ushort* Wo2 = (ushort*)(ws + 43008 + 79872 + 16384);  // need 36864 ush
    float* dyb = ws + 172032;
    float* dxb = dyb + 589824;
    float* mob = dxb + 589824;
    float* hbuf = mob + 589824;      // 8388608 f: h1, later reused as h2
    float* xhf = hbuf + 8388608;     // 2097152 f: x as NHWC bf16
    float* h1hf = xhf + 2097152;     // 4194304 f: h1 as NHWC bf16
    float* praw = h1hf + 4194304;    // 2048 (8 replicas x 256)
    ushort* xh = (ushort*)xhf;
    ushort* h1h = (ushort*)h1hf;

    prep_weights<<<1176, 256, 0, stream>>>(w1, w2, w_off1, w_mod1, w_off2,
                                           w_mod2, Wt1, Wt2, Wo1, Wo2);

    // ---- stage 1 ----
    nhwc_cvt<64><<<1024, 256, 0, stream>>>(x, (unsigned*)xh);
    offmod_nhwc<64><<<1024, 256, 0, stream>>>(xh, Wo1, b_off1, b_mod1, dyb, dxb,
                                              mob, praw);
    deform_mfma5<64><<<1024, 512, 0, stream>>>(xh, dyb, dxb, mob, Wt1, hbuf,
                                               praw);
    bn_apply_cvt<128><<<1024, 256, 0, stream>>>(hbuf, praw, (unsigned*)h1h);

    // ---- stage 2 ----
    offmod_nhwc<128><<<1024, 256, 0, stream>>>(h1h, Wo2, b_off2, b_mod2, dyb,
                                               dxb, mob, praw);
    // hbuf (h1 fp32) is dead after bn_apply_cvt: deform2 writes h2 into it
    deform_mfma5<128><<<1024, 512, 0, stream>>>(h1h, dyb, dxb, mob, Wt2, hbuf,
                                                praw);
    bn_pool<<<8192, 256, 0, stream>>>(hbuf, praw, out, 4, 128);
}

// Round 15
// 294.741 us; speedup vs baseline: 1.0487x; 1.0487x over previous
//
#include <hip/hip_runtime.h>
#include <math.h>

#define HH 128
#define WW 128
#define HWSZ 16384

typedef __attribute__((ext_vector_type(8))) short short8;
typedef __attribute__((ext_vector_type(4))) float f32x4;
typedef __attribute__((ext_vector_type(2))) float f32x2;
typedef unsigned short ushort;

__device__ __forceinline__ ushort f2bf(float f) {
    unsigned int u = __float_as_uint(f);
    unsigned int r = u + 0x7fffu + ((u >> 16) & 1u);
    return (ushort)(r >> 16);
}
// pack two floats -> packed bf16 dword (lo in [15:0], hi in [31:16]), RNE.
// Uses gfx950 v_cvt_pk_bf16_f32 when available (1 instr vs ~8).
__device__ __forceinline__ unsigned f2bf2(float lo, float hi) {
#if __has_builtin(__builtin_amdgcn_cvt_pk_bf16_f32)
    auto r = __builtin_amdgcn_cvt_pk_bf16_f32(lo, hi);
    unsigned u;
    __builtin_memcpy(&u, &r, 4);
    return u;
#else
    return (unsigned)f2bf(lo) | ((unsigned)f2bf(hi) << 16);
#endif
}
// unpack 2 packed bf16 (one dword) to float2: .x = low half, .y = high half
__device__ __forceinline__ f32x2 unpk(unsigned u) {
    return (f32x2){__uint_as_float(u << 16),
                   __uint_as_float(u & 0xffff0000u)};
}

// ---- merged weight prep: wpad1 | wpad2 | woff1 | woff2 in one launch ----
__global__ __launch_bounds__(256) void prep_weights(
    const float* __restrict__ w1, const float* __restrict__ w2,
    const float* __restrict__ w_off1, const float* __restrict__ w_mod1,
    const float* __restrict__ w_off2, const float* __restrict__ w_mod2,
    ushort* __restrict__ Wt1, ushort* __restrict__ Wt2,
    ushort* __restrict__ Wo1, ushort* __restrict__ Wo2) {
    int bid = blockIdx.x, tid = threadIdx.x;
    if (bid < 336) {
        int i = bid * 256 + tid;
        int o = i / 672, kq = i % 672;
        int k = kq / 72, c = kq % 72;
        float v = (k < 9 && c < 64) ? w1[(o * 64 + c) * 9 + k] : 0.f;
        Wt1[i] = f2bf(v);
    } else if (bid < 960) {
        int i = (bid - 336) * 256 + tid;
        int o = i / 1248, kq = i % 1248;
        int k = kq / 136, c = kq % 136;
        float v = (k < 9 && c < 128) ? w2[(o * 128 + c) * 9 + k] : 0.f;
        Wt2[i] = f2bf(v);
    } else if (bid < 1032) {
        int i = (bid - 960) * 256 + tid;  // < 32*576
        int o = i / 576, kap = i % 576;
        int k = kap / 64, c = kap % 64;
        float v = 0.f;
        if (o < 18) v = w_off1[(o * 64 + c) * 9 + k];
        else if (o < 27) v = w_mod1[((o - 18) * 64 + c) * 9 + k];
        Wo1[i] = f2bf(v);
    } else {
        int i = (bid - 1032) * 256 + tid;  // < 32*1152
        int o = i / 1152, kap = i % 1152;
        int k = kap / 128, c = kap % 128;
        float v = 0.f;
        if (o < 18) v = w_off2[(o * 128 + c) * 9 + k];
        else if (o < 27) v = w_mod2[((o - 18) * 128 + c) * 9 + k];
        Wo2[i] = f2bf(v);
    }
}

// ---- NCHW fp32 -> NHWC bf16 converter (tiled transpose) ----
template <int C>
__global__ __launch_bounds__(256) void nhwc_cvt(const float* __restrict__ xin,
                                                unsigned* __restrict__ xout) {
    __shared__ float tile[64][C + 1];
    const int m0 = blockIdx.x * 64;
    const int b = m0 >> 14;
    const int hw0 = m0 & 16383;
    const int t = threadIdx.x;
    const int pr = t & 63, cr = t >> 6;
#pragma unroll
    for (int it = 0; it < C / 4; ++it) {
        int c = it * 4 + cr;
        tile[pr][c] = xin[(((size_t)(b * C + c)) << 14) + hw0 + pr];
    }
    __syncthreads();
    constexpr int CH = C / 2;
#pragma unroll
    for (int it = 0; it < 64 * CH / 256; ++it) {
        int slot = it * 256 + t;
        int p = slot / CH, cc = slot % CH;
        xout[(size_t)(m0 + p) * CH + cc] =
            f2bf2(tile[p][2 * cc], tile[p][2 * cc + 1]);
    }
}

// ---- fused bn finalize(from praw replicas) + norm/relu + NHWC bf16 cvt ----
template <int C>
__global__ __launch_bounds__(256) void bn_apply_cvt(
    const float* __restrict__ xin, const float* __restrict__ praw,
    unsigned* __restrict__ xout) {
    __shared__ float tile[64][C + 1];
    __shared__ float lstats[256];
    const int t = threadIdx.x;
    if (t < 128) {
        float s = 0.f, q = 0.f;
#pragma unroll
        for (int r = 0; r < 8; ++r) {
            s += praw[r * 256 + t];
            q += praw[r * 256 + 128 + t];
        }
        float mean = s / 65536.f;
        float var = q / 65536.f - mean * mean;
        lstats[t] = mean;
        lstats[128 + t] = rsqrtf(var + 1e-5f);
    }
    __syncthreads();
    const int m0 = blockIdx.x * 64;
    const int b = m0 >> 14;
    const int hw0 = m0 & 16383;
    const int pr = t & 63, cr = t >> 6;
#pragma unroll
    for (int it = 0; it < C / 4; ++it) {
        int c = it * 4 + cr;
        float v = xin[(((size_t)(b * C + c)) << 14) + hw0 + pr];
        tile[pr][c] = fmaxf(0.f, (v - lstats[c]) * lstats[C + c]);
    }
    __syncthreads();
    constexpr int CH = C / 2;
#pragma unroll
    for (int it = 0; it < 64 * CH / 256; ++it) {
        int slot = it * 256 + t;
        int p = slot / CH, cc = slot % CH;
        xout[(size_t)(m0 + p) * CH + cc] =
            f2bf2(tile[p][2 * cc], tile[p][2 * cc + 1]);
    }
}

// ---- offset/mod conv: NHWC-bf16 direct A-fragment MFMA GEMM ----
// also zeroes the bn praw replicas (blocks 0..7) for the following deform.
template <int C>
__global__ __launch_bounds__(256) void offmod_nhwc(
    const ushort* __restrict__ xh, const ushort* __restrict__ wt,
    const float* __restrict__ b_off, const float* __restrict__ b_mod,
    float* __restrict__ dyb, float* __restrict__ dxb, float* __restrict__ mob,
    float* __restrict__ praw) {
    constexpr int K = C * 9;
    if (blockIdx.x < 8) praw[blockIdx.x * 256 + threadIdx.x] = 0.f;
    const int m0 = blockIdx.x * 64;
    const int b = m0 >> 14;
    const int hw0 = m0 & 16383;
    const int h = hw0 >> 7;
    const int w0 = hw0 & 127;
    const int tid = threadIdx.x;
    const int lane = tid & 63, wv = tid >> 6;
    const int n16 = lane & 15, quad = lane >> 4;
    const int p = wv * 16 + n16;
    const int w = w0 + p;

    int tbase[9];
    bool tval[9];
#pragma unroll
    for (int k = 0; k < 9; ++k) {
        int yy = h + k / 3 - 1, xx = w + k % 3 - 1;
        tval[k] = ((unsigned)yy < 128u) && ((unsigned)xx < 128u);
        int cy = min(max(yy, 0), 127), cx = min(max(xx, 0), 127);
        tbase[k] = ((b << 14) + (cy << 7) + cx) * C + quad * 8;
    }

    f32x4 acc[2];
    acc[0] = (f32x4){0.f, 0.f, 0.f, 0.f};
    acc[1] = (f32x4){0.f, 0.f, 0.f, 0.f};

    const ushort* b0p = wt + (size_t)n16 * K + quad * 8;
    const ushort* b1p = wt + (size_t)(16 + n16) * K + quad * 8;

#pragma unroll
    for (int s = 0; s < K / 32; ++s) {
        const int k = (s * 32) / C;
        const int c0 = (s * 32) % C;
        short8 a = (short8){0, 0, 0, 0, 0, 0, 0, 0};
        if (tval[k]) a = *(const short8*)(xh + (size_t)tbase[k] + c0);
        const short8 bv0 = *(const short8*)(b0p + s * 32);
        const short8 bv1 = *(const short8*)(b1p + s * 32);
        acc[0] = __builtin_amdgcn_mfma_f32_16x16x32_bf16(a, bv0, acc[0], 0, 0, 0);
        acc[1] = __builtin_amdgcn_mfma_f32_16x16x32_bf16(a, bv1, acc[1], 0, 0, 0);
    }

    __shared__ float sm[32 * 65];
#pragma unroll
    for (int nt = 0; nt < 2; ++nt) {
        int n = nt * 16 + n16;
        int pb = wv * 16 + quad * 4;
#pragma unroll
        for (int r = 0; r < 4; ++r) sm[n * 65 + pb + r] = acc[nt][r];
    }
    __syncthreads();
    {
        int n = tid >> 3, i8 = tid & 7;
        if (n < 27) {
            const float* sp = sm + n * 65 + i8 * 8;
            int px = hw0 + i8 * 8;
            if (n < 18) {
                int k = n >> 1;
                float bias = b_off[n];
                float* dst =
                    ((n & 1) ? dxb : dyb) + (((size_t)(b * 9 + k)) << 14) + px;
#pragma unroll
                for (int j = 0; j < 8; j += 4) {
                    float4 v = make_float4(sp[j] + bias, sp[j + 1] + bias,
                                           sp[j + 2] + bias, sp[j + 3] + bias);
                    *(float4*)(dst + j) = v;
                }
            } else {
                float bias = b_mod[n - 18];
                float* dst = mob + (((size_t)(b * 9 + (n - 18))) << 14) + px;
#pragma unroll
                for (int j = 0; j < 8; j += 4) {
                    float4 v;
                    v.x = 2.f / (1.f + expf(-(sp[j] + bias)));
                    v.y = 2.f / (1.f + expf(-(sp[j + 1] + bias)));
                    v.z = 2.f / (1.f + expf(-(sp[j + 2] + bias)));
                    v.w = 2.f / (1.f + expf(-(sp[j + 3] + bias)));
                    *(float4*)(dst + j) = v;
                }
            }
        }
    }
}

// ---- deformable conv v3 (green R10/R13): K-chunked double-buffered GEMM ----
// + fused bn partial stats into 8 praw replicas.
template <int C>
__global__ __launch_bounds__(256) void deform_mfma3(
    const ushort* __restrict__ xh, const float* __restrict__ dyb,
    const float* __restrict__ dxb, const float* __restrict__ mob,
    const ushort* __restrict__ wt, float* __restrict__ out,
    float* __restrict__ praw) {
    constexpr int PIX = 32;
    constexpr int AST = C + 8;
    constexpr int CPW = C + 8;
    constexpr int KP = ((9 * CPW + 31) / 32) * 32;
    constexpr int NCC = C / 8;
    constexpr int NIT = PIX * NCC / 256;
    constexpr int ABUF = PIX * AST;

    __shared__ __align__(16) char smem_raw[2 * ABUF * 2 + PIX * 9 * 32];
    ushort* abuf0 = (ushort*)smem_raw;
    ushort* abuf1 = abuf0 + ABUF;
    int* tb = (int*)(abuf0 + 2 * ABUF);
    float* tw = (float*)(tb + PIX * 9 * 4);

    const int m0 = blockIdx.x * PIX;
    const int b = m0 >> 14;
    const int hw0 = m0 & 16383;
    const int h = hw0 >> 7, w0 = hw0 & 127;
    const int tid = threadIdx.x;

    for (int r = tid; r < PIX * 9; r += 256) {
        int p = r & (PIX - 1), k = r / PIX;
        int oi = ((b * 9 + k) << 14) + hw0 + p;
        float py = (float)(h + k / 3 - 1) + dyb[oi];
        float px = (float)(w0 + p + k % 3 - 1) + dxb[oi];
        float mv = mob[oi];
        float y0f = floorf(py), x0f = floorf(px);
        float wy = py - y0f, wx = px - x0f;
        int y0 = (int)y0f, x0 = (int)x0f;
        int y1 = y0 + 1, x1 = x0 + 1;
        float f00 = (1.f - wy) * (1.f - wx) *
                    (((unsigned)y0 < 128u && (unsigned)x0 < 128u) ? mv : 0.f);
        float f01 = (1.f - wy) * wx *
                    (((unsigned)y0 < 128u && (unsigned)x1 < 128u) ? mv : 0.f);
        float f10 = wy * (1.f - wx) *
                    (((unsigned)y1 < 128u && (unsigned)x0 < 128u) ? mv : 0.f);
        float f11 = wy * wx *
                    (((unsigned)y1 < 128u && (unsigned)x1 < 128u) ? mv : 0.f);
        int cy0 = min(max(y0, 0), 127), cy1 = min(max(y1, 0), 127);
        int cx0 = min(max(x0, 0), 127), cx1 = min(max(x1, 0), 127);
        int bpx = b << 14;
        int s = (p * 9 + k) * 4;
        tb[s + 0] = (bpx + (cy0 << 7) + cx0) * C;
        tb[s + 1] = (bpx + (cy0 << 7) + cx1) * C;
        tb[s + 2] = (bpx + (cy1 << 7) + cx0) * C;
        tb[s + 3] = (bpx + (cy1 << 7) + cx1) * C;
        tw[s + 0] = f00;
        tw[s + 1] = f01;
        tw[s + 2] = f10;
        tw[s + 3] = f11;
    }
    __syncthreads();

    auto issue_loads = [&](int kc, uint4 (&q)[2][4], float4 (&fw)[2]) {
#pragma unroll
        for (int it = 0; it < NIT; ++it) {
            int e = it * 256 + tid;
            int p = e / NCC, cc = e % NCC;
            int s = (p * 9 + kc) * 4;
            int4 bi = *(const int4*)&tb[s];
            fw[it] = *(const float4*)&tw[s];
            q[it][0] = *(const uint4*)(xh + (size_t)bi.x + cc * 8);
            q[it][1] = *(const uint4*)(xh + (size_t)bi.y + cc * 8);
            q[it][2] = *(const uint4*)(xh + (size_t)bi.z + cc * 8);
            q[it][3] = *(const uint4*)(xh + (size_t)bi.w + cc * 8);
        }
    };
    auto interp_write = [&](ushort* dst, uint4 (&q)[2][4], float4 (&fw)[2]) {
#pragma unroll
        for (int it = 0; it < NIT; ++it) {
            int e = it * 256 + tid;
            int p = e / NCC, cc = e % NCC;
            unsigned a0[4] = {q[it][0].x, q[it][0].y, q[it][0].z, q[it][0].w};
            unsigned a1[4] = {q[it][1].x, q[it][1].y, q[it][1].z, q[it][1].w};
            unsigned a2[4] = {q[it][2].x, q[it][2].y, q[it][2].z, q[it][2].w};
            unsigned a3[4] = {q[it][3].x, q[it][3].y, q[it][3].z, q[it][3].w};
            unsigned ov[4];
#pragma unroll
            for (int dw = 0; dw < 4; ++dw) {
                f32x2 v = unpk(a0[dw]) * fw[it].x;
                v += unpk(a1[dw]) * fw[it].y;
                v += unpk(a2[dw]) * fw[it].z;
                v += unpk(a3[dw]) * fw[it].w;
                ov[dw] = f2bf2(v.x, v.y);
            }
            *(uint4*)&dst[p * AST + cc * 8] = uint4{ov[0], ov[1], ov[2], ov[3]};
        }
    };

    {
        uint4 q[2][4];
        float4 fw[2];
        issue_loads(0, q, fw);
        interp_write(abuf0, q, fw);
    }
    __syncthreads();

    const int lane = tid & 63, wv = tid >> 6;
    const int n16 = lane & 15, quad = lane >> 4;

    f32x4 acc[2][2];
#pragma unroll
    for (int mt = 0; mt < 2; ++mt)
#pragma unroll
        for (int nt = 0; nt < 2; ++nt) acc[mt][nt] = (f32x4){0.f, 0.f, 0.f, 0.f};

    const ushort* bbase[2];
#pragma unroll
    for (int nt = 0; nt < 2; ++nt)
        bbase[nt] = wt + (size_t)(wv * 32 + nt * 16 + n16) * KP + quad * 8;

#pragma unroll 1
    for (int kc = 0; kc < 9; ++kc) {
        uint4 q[2][4];
        float4 fw[2];
        if (kc < 8) issue_loads(kc + 1, q, fw);

        const ushort* ab = (kc & 1) ? abuf1 : abuf0;
#pragma unroll
        for (int s = 0; s < C / 32; ++s) {
            short8 av[2], bv[2];
#pragma unroll
            for (int mt = 0; mt < 2; ++mt)
                av[mt] = *(const short8*)(ab + (mt * 16 + n16) * AST + s * 32 +
                                          quad * 8);
#pragma unroll
            for (int nt = 0; nt < 2; ++nt)
                bv[nt] = *(const short8*)(bbase[nt] + kc * CPW + s * 32);
#pragma unroll
            for (int mt = 0; mt < 2; ++mt)
#pragma unroll
                for (int nt = 0; nt < 2; ++nt)
                    acc[mt][nt] = __builtin_amdgcn_mfma_f32_16x16x32_bf16(
                        av[mt], bv[nt], acc[mt][nt], 0, 0, 0);
        }
        if (kc < 8)
            interp_write((kc & 1) ? abuf0 : abuf1, q, fw);
        __syncthreads();
    }

    // ---- epilogue: transpose via LDS; stores + fused bn partial stats ----
    float* sm = (float*)smem_raw;
    constexpr int SROW = PIX + 1;
#pragma unroll
    for (int mt = 0; mt < 2; ++mt)
#pragma unroll
        for (int nt = 0; nt < 2; ++nt) {
            int o = wv * 32 + nt * 16 + n16;
            int mb = mt * 16 + quad * 4;
#pragma unroll
            for (int r = 0; r < 4; ++r) sm[o * SROW + mb + r] = acc[mt][nt][r];
        }
    __syncthreads();
    {
        int o = tid >> 1, half = tid & 1;
        constexpr int HP = PIX / 2;
        const float* sp = sm + o * SROW + half * HP;
        float* op = out + (((size_t)(b * 128 + o)) << 14) + hw0 + half * HP;
        float s = 0.f, qq = 0.f;
#pragma unroll
        for (int i = 0; i < HP; i += 4) {
            float4 v = make_float4(sp[i], sp[i + 1], sp[i + 2], sp[i + 3]);
            *(float4*)(op + i) = v;
            s += v.x + v.y + v.z + v.w;
            qq += v.x * v.x + v.y * v.y + v.z * v.z + v.w * v.w;
        }
        s += __shfl_down(s, 1, 64);
        qq += __shfl_down(qq, 1, 64);
        if (half == 0) {
            float* pr = praw + (blockIdx.x & 7) * 256;
            atomicAdd(&pr[o], s);
            atomicAdd(&pr[128 + o], qq);
        }
    }
}

// ---- fused bn finalize + bn + relu + 2x2 maxpool ----
__global__ __launch_bounds__(256) void bn_pool(const float* __restrict__ x,
                                               const float* __restrict__ praw,
                                               float* __restrict__ out, int B,
                                               int C) {
    __shared__ float lstats[256];
    if (threadIdx.x < 128) {
        int c = threadIdx.x;
        float s = 0.f, q = 0.f;
#pragma unroll
        for (int r = 0; r < 8; ++r) {
            s += praw[r * 256 + c];
            q += praw[r * 256 + 128 + c];
        }
        float mean = s / 65536.f;
        float var = q / 65536.f - mean * mean;
        lstats[c] = mean;
        lstats[128 + c] = rsqrtf(var + 1e-5f);
    }
    __syncthreads();
    const int Ho = 64, Wo = 64;
    int i = blockIdx.x * blockDim.x + threadIdx.x;
    int total = B * C * Ho * Wo;
    if (i >= total) return;
    int ow = i % Wo;
    int t = i / Wo;
    int oh = t % Ho;
    t /= Ho;
    int c = t % C;
    int b = t / C;
    const float* p = x + ((size_t)(b * C + c)) * HWSZ + (2 * oh) * WW + 2 * ow;
    float m0 = fmaxf(p[0], p[1]);
    float m1 = fmaxf(p[WW], p[WW + 1]);
    float mx = fmaxf(m0, m1);
    out[i] = fmaxf(0.f, (mx - lstats[c]) * lstats[C + c]);
}

extern "C" void kernel_launch(void* const* d_in, const int* in_sizes, int n_in,
                              void* d_out, int out_size, void* d_ws,
                              size_t ws_size, hipStream_t stream) {
    (void)in_sizes;
    (void)n_in;
    (void)out_size;
    (void)ws_size;
    const float* x = (const float*)d_in[0];
    const float* w_off1 = (const float*)d_in[1];
    const float* b_off1 = (const float*)d_in[2];
    const float* w_mod1 = (const float*)d_in[3];
    const float* b_mod1 = (const float*)d_in[4];
    const float* w1 = (const float*)d_in[5];
    const float* w_off2 = (const float*)d_in[6];
    const float* b_off2 = (const float*)d_in[7];
    const float* w_mod2 = (const float*)d_in[8];
    const float* b_mod2 = (const float*)d_in[9];
    const float* w2 = (const float*)d_in[10];
    float* out = (float*)d_out;
    float* ws = (float*)d_ws;

    // KP1 = 672 (C=64, CP=72), KP2 = 1248 (C=128, CP=136)
    ushort* Wt1 = (ushort*)ws;                            // 86016 ush = 43008 f
    ushort* Wt2 = (ushort*)(ws + 43008);                  // 159744 ush = 79872 f
    ushort* Wo1 = (ushort*)(ws + 43008 + 79872);          // need 18432 ush
    ushort* Wo2 = (ushort*)(ws + 43008 + 79872 + 16384);  // need 36864 ush
    float* dyb = ws + 172032;
    float* dxb = dyb + 589824;
    float* mob = dxb + 589824;
    float* hbuf = mob + 589824;      // 8388608 f: h1, later reused as h2
    float* xhf = hbuf + 8388608;     // 2097152 f: x as NHWC bf16
    float* h1hf = xhf + 2097152;     // 4194304 f: h1 as NHWC bf16
    float* praw = h1hf + 4194304;    // 2048 (8 replicas x 256)
    ushort* xh = (ushort*)xhf;
    ushort* h1h = (ushort*)h1hf;

    prep_weights<<<1176, 256, 0, stream>>>(w1, w2, w_off1, w_mod1, w_off2,
                                           w_mod2, Wt1, Wt2, Wo1, Wo2);

    // ---- stage 1 ----
    nhwc_cvt<64><<<1024, 256, 0, stream>>>(x, (unsigned*)xh);
    offmod_nhwc<64><<<1024, 256, 0, stream>>>(xh, Wo1, b_off1, b_mod1, dyb, dxb,
                                              mob, praw);
    deform_mfma3<64><<<2048, 256, 0, stream>>>(xh, dyb, dxb, mob, Wt1, hbuf,
                                               praw);
    bn_apply_cvt<128><<<1024, 256, 0, stream>>>(hbuf, praw, (unsigned*)h1h);

    // ---- stage 2 ----
    offmod_nhwc<128><<<1024, 256, 0, stream>>>(h1h, Wo2, b_off2, b_mod2, dyb,
                                               dxb, mob, praw);
    // hbuf (h1 fp32) is dead after bn_apply_cvt: deform2 writes h2 into it
    deform_mfma3<128><<<2048, 256, 0, stream>>>(h1h, dyb, dxb, mob, Wt2, hbuf,
                                                praw);
    bn_pool<<<8192, 256, 0, stream>>>(hbuf, praw, out, 4, 128);
}

// Round 16
// 287.721 us; speedup vs baseline: 1.0743x; 1.0244x over previous
//
#include <hip/hip_runtime.h>
#include <math.h>

#define HH 128
#define WW 128
#define HWSZ 16384

typedef __attribute__((ext_vector_type(8))) short short8;
typedef __attribute__((ext_vector_type(4))) float f32x4;
typedef __attribute__((ext_vector_type(2))) float f32x2;
typedef unsigned short ushort;

__device__ __forceinline__ ushort f2bf(float f) {
    unsigned int u = __float_as_uint(f);
    unsigned int r = u + 0x7fffu + ((u >> 16) & 1u);
    return (ushort)(r >> 16);
}
// pack two floats -> packed bf16 dword (lo in [15:0], hi in [31:16]), RNE.
__device__ __forceinline__ unsigned f2bf2(float lo, float hi) {
#if __has_builtin(__builtin_amdgcn_cvt_pk_bf16_f32)
    auto r = __builtin_amdgcn_cvt_pk_bf16_f32(lo, hi);
    unsigned u;
    __builtin_memcpy(&u, &r, 4);
    return u;
#else
    return (unsigned)f2bf(lo) | ((unsigned)f2bf(hi) << 16);
#endif
}
// unpack 2 packed bf16 (one dword) to float2: .x = low half, .y = high half
__device__ __forceinline__ f32x2 unpk(unsigned u) {
    return (f32x2){__uint_as_float(u << 16),
                   __uint_as_float(u & 0xffff0000u)};
}

// ---- merged weight prep: wpad1 | wpad2 | woff1 | woff2 in one launch ----
__global__ __launch_bounds__(256) void prep_weights(
    const float* __restrict__ w1, const float* __restrict__ w2,
    const float* __restrict__ w_off1, const float* __restrict__ w_mod1,
    const float* __restrict__ w_off2, const float* __restrict__ w_mod2,
    ushort* __restrict__ Wt1, ushort* __restrict__ Wt2,
    ushort* __restrict__ Wo1, ushort* __restrict__ Wo2) {
    int bid = blockIdx.x, tid = threadIdx.x;
    if (bid < 336) {
        int i = bid * 256 + tid;
        int o = i / 672, kq = i % 672;
        int k = kq / 72, c = kq % 72;
        float v = (k < 9 && c < 64) ? w1[(o * 64 + c) * 9 + k] : 0.f;
        Wt1[i] = f2bf(v);
    } else if (bid < 960) {
        int i = (bid - 336) * 256 + tid;
        int o = i / 1248, kq = i % 1248;
        int k = kq / 136, c = kq % 136;
        float v = (k < 9 && c < 128) ? w2[(o * 128 + c) * 9 + k] : 0.f;
        Wt2[i] = f2bf(v);
    } else if (bid < 1032) {
        int i = (bid - 960) * 256 + tid;  // < 32*576
        int o = i / 576, kap = i % 576;
        int k = kap / 64, c = kap % 64;
        float v = 0.f;
        if (o < 18) v = w_off1[(o * 64 + c) * 9 + k];
        else if (o < 27) v = w_mod1[((o - 18) * 64 + c) * 9 + k];
        Wo1[i] = f2bf(v);
    } else {
        int i = (bid - 1032) * 256 + tid;  // < 32*1152
        int o = i / 1152, kap = i % 1152;
        int k = kap / 128, c = kap % 128;
        float v = 0.f;
        if (o < 18) v = w_off2[(o * 128 + c) * 9 + k];
        else if (o < 27) v = w_mod2[((o - 18) * 128 + c) * 9 + k];
        Wo2[i] = f2bf(v);
    }
}

// ---- NCHW fp32 -> NHWC bf16 converter (tiled transpose) ----
template <int C>
__global__ __launch_bounds__(256) void nhwc_cvt(const float* __restrict__ xin,
                                                unsigned* __restrict__ xout) {
    __shared__ float tile[64][C + 1];
    const int m0 = blockIdx.x * 64;
    const int b = m0 >> 14;
    const int hw0 = m0 & 16383;
    const int t = threadIdx.x;
    const int pr = t & 63, cr = t >> 6;
#pragma unroll
    for (int it = 0; it < C / 4; ++it) {
        int c = it * 4 + cr;
        tile[pr][c] = xin[(((size_t)(b * C + c)) << 14) + hw0 + pr];
    }
    __syncthreads();
    constexpr int CH = C / 2;
#pragma unroll
    for (int it = 0; it < 64 * CH / 256; ++it) {
        int slot = it * 256 + t;
        int p = slot / CH, cc = slot % CH;
        xout[(size_t)(m0 + p) * CH + cc] =
            f2bf2(tile[p][2 * cc], tile[p][2 * cc + 1]);
    }
}

// ---- fused bn finalize(from praw replicas) + norm/relu + NHWC bf16 cvt ----
template <int C>
__global__ __launch_bounds__(256) void bn_apply_cvt(
    const float* __restrict__ xin, const float* __restrict__ praw,
    unsigned* __restrict__ xout) {
    __shared__ float tile[64][C + 1];
    __shared__ float lstats[256];
    const int t = threadIdx.x;
    if (t < 128) {
        float s = 0.f, q = 0.f;
#pragma unroll
        for (int r = 0; r < 8; ++r) {
            s += praw[r * 256 + t];
            q += praw[r * 256 + 128 + t];
        }
        float mean = s / 65536.f;
        float var = q / 65536.f - mean * mean;
        lstats[t] = mean;
        lstats[128 + t] = rsqrtf(var + 1e-5f);
    }
    __syncthreads();
    const int m0 = blockIdx.x * 64;
    const int b = m0 >> 14;
    const int hw0 = m0 & 16383;
    const int pr = t & 63, cr = t >> 6;
#pragma unroll
    for (int it = 0; it < C / 4; ++it) {
        int c = it * 4 + cr;
        float v = xin[(((size_t)(b * C + c)) << 14) + hw0 + pr];
        tile[pr][c] = fmaxf(0.f, (v - lstats[c]) * lstats[C + c]);
    }
    __syncthreads();
    constexpr int CH = C / 2;
#pragma unroll
    for (int it = 0; it < 64 * CH / 256; ++it) {
        int slot = it * 256 + t;
        int p = slot / CH, cc = slot % CH;
        xout[(size_t)(m0 + p) * CH + cc] =
            f2bf2(tile[p][2 * cc], tile[p][2 * cc + 1]);
    }
}

// ---- offset/mod conv: NHWC-bf16 direct A-fragment MFMA GEMM ----
// also zeroes the bn praw replicas (blocks 0..7) for the following deform.
template <int C>
__global__ __launch_bounds__(256) void offmod_nhwc(
    const ushort* __restrict__ xh, const ushort* __restrict__ wt,
    const float* __restrict__ b_off, const float* __restrict__ b_mod,
    float* __restrict__ dyb, float* __restrict__ dxb, float* __restrict__ mob,
    float* __restrict__ praw) {
    constexpr int K = C * 9;
    if (blockIdx.x < 8) praw[blockIdx.x * 256 + threadIdx.x] = 0.f;
    const int m0 = blockIdx.x * 64;
    const int b = m0 >> 14;
    const int hw0 = m0 & 16383;
    const int h = hw0 >> 7;
    const int w0 = hw0 & 127;
    const int tid = threadIdx.x;
    const int lane = tid & 63, wv = tid >> 6;
    const int n16 = lane & 15, quad = lane >> 4;
    const int p = wv * 16 + n16;
    const int w = w0 + p;

    int tbase[9];
    bool tval[9];
#pragma unroll
    for (int k = 0; k < 9; ++k) {
        int yy = h + k / 3 - 1, xx = w + k % 3 - 1;
        tval[k] = ((unsigned)yy < 128u) && ((unsigned)xx < 128u);
        int cy = min(max(yy, 0), 127), cx = min(max(xx, 0), 127);
        tbase[k] = ((b << 14) + (cy << 7) + cx) * C + quad * 8;
    }

    f32x4 acc[2];
    acc[0] = (f32x4){0.f, 0.f, 0.f, 0.f};
    acc[1] = (f32x4){0.f, 0.f, 0.f, 0.f};

    const ushort* b0p = wt + (size_t)n16 * K + quad * 8;
    const ushort* b1p = wt + (size_t)(16 + n16) * K + quad * 8;

#pragma unroll
    for (int s = 0; s < K / 32; ++s) {
        const int k = (s * 32) / C;
        const int c0 = (s * 32) % C;
        short8 a = (short8){0, 0, 0, 0, 0, 0, 0, 0};
        if (tval[k]) a = *(const short8*)(xh + (size_t)tbase[k] + c0);
        const short8 bv0 = *(const short8*)(b0p + s * 32);
        const short8 bv1 = *(const short8*)(b1p + s * 32);
        acc[0] = __builtin_amdgcn_mfma_f32_16x16x32_bf16(a, bv0, acc[0], 0, 0, 0);
        acc[1] = __builtin_amdgcn_mfma_f32_16x16x32_bf16(a, bv1, acc[1], 0, 0, 0);
    }

    __shared__ float sm[32 * 65];
#pragma unroll
    for (int nt = 0; nt < 2; ++nt) {
        int n = nt * 16 + n16;
        int pb = wv * 16 + quad * 4;
#pragma unroll
        for (int r = 0; r < 4; ++r) sm[n * 65 + pb + r] = acc[nt][r];
    }
    __syncthreads();
    {
        int n = tid >> 3, i8 = tid & 7;
        if (n < 27) {
            const float* sp = sm + n * 65 + i8 * 8;
            int px = hw0 + i8 * 8;
            if (n < 18) {
                int k = n >> 1;
                float bias = b_off[n];
                float* dst =
                    ((n & 1) ? dxb : dyb) + (((size_t)(b * 9 + k)) << 14) + px;
#pragma unroll
                for (int j = 0; j < 8; j += 4) {
                    float4 v = make_float4(sp[j] + bias, sp[j + 1] + bias,
                                           sp[j + 2] + bias, sp[j + 3] + bias);
                    *(float4*)(dst + j) = v;
                }
            } else {
                float bias = b_mod[n - 18];
                float* dst = mob + (((size_t)(b * 9 + (n - 18))) << 14) + px;
#pragma unroll
                for (int j = 0; j < 8; j += 4) {
                    float4 v;
                    v.x = 2.f / (1.f + expf(-(sp[j] + bias)));
                    v.y = 2.f / (1.f + expf(-(sp[j + 1] + bias)));
                    v.z = 2.f / (1.f + expf(-(sp[j + 2] + bias)));
                    v.w = 2.f / (1.f + expf(-(sp[j + 3] + bias)));
                    *(float4*)(dst + j) = v;
                }
            }
        }
    }
}

// ---- deformable conv v3 (stage 1): K-chunked double-buffered GEMM ----
// + fused bn partial stats into 8 praw replicas. 32 pixels = row segment.
template <int C>
__global__ __launch_bounds__(256) void deform_mfma3(
    const ushort* __restrict__ xh, const float* __restrict__ dyb,
    const float* __restrict__ dxb, const float* __restrict__ mob,
    const ushort* __restrict__ wt, float* __restrict__ out,
    float* __restrict__ praw) {
    constexpr int PIX = 32;
    constexpr int AST = C + 8;
    constexpr int CPW = C + 8;
    constexpr int KP = ((9 * CPW + 31) / 32) * 32;
    constexpr int NCC = C / 8;
    constexpr int NIT = PIX * NCC / 256;
    constexpr int ABUF = PIX * AST;

    __shared__ __align__(16) char smem_raw[2 * ABUF * 2 + PIX * 9 * 32];
    ushort* abuf0 = (ushort*)smem_raw;
    ushort* abuf1 = abuf0 + ABUF;
    int* tb = (int*)(abuf0 + 2 * ABUF);
    float* tw = (float*)(tb + PIX * 9 * 4);

    const int m0 = blockIdx.x * PIX;
    const int b = m0 >> 14;
    const int hw0 = m0 & 16383;
    const int h = hw0 >> 7, w0 = hw0 & 127;
    const int tid = threadIdx.x;

    for (int r = tid; r < PIX * 9; r += 256) {
        int p = r & (PIX - 1), k = r / PIX;
        int oi = ((b * 9 + k) << 14) + hw0 + p;
        float py = (float)(h + k / 3 - 1) + dyb[oi];
        float px = (float)(w0 + p + k % 3 - 1) + dxb[oi];
        float mv = mob[oi];
        float y0f = floorf(py), x0f = floorf(px);
        float wy = py - y0f, wx = px - x0f;
        int y0 = (int)y0f, x0 = (int)x0f;
        int y1 = y0 + 1, x1 = x0 + 1;
        float f00 = (1.f - wy) * (1.f - wx) *
                    (((unsigned)y0 < 128u && (unsigned)x0 < 128u) ? mv : 0.f);
        float f01 = (1.f - wy) * wx *
                    (((unsigned)y0 < 128u && (unsigned)x1 < 128u) ? mv : 0.f);
        float f10 = wy * (1.f - wx) *
                    (((unsigned)y1 < 128u && (unsigned)x0 < 128u) ? mv : 0.f);
        float f11 = wy * wx *
                    (((unsigned)y1 < 128u && (unsigned)x1 < 128u) ? mv : 0.f);
        int cy0 = min(max(y0, 0), 127), cy1 = min(max(y1, 0), 127);
        int cx0 = min(max(x0, 0), 127), cx1 = min(max(x1, 0), 127);
        int bpx = b << 14;
        int s = (p * 9 + k) * 4;
        tb[s + 0] = (bpx + (cy0 << 7) + cx0) * C;
        tb[s + 1] = (bpx + (cy0 << 7) + cx1) * C;
        tb[s + 2] = (bpx + (cy1 << 7) + cx0) * C;
        tb[s + 3] = (bpx + (cy1 << 7) + cx1) * C;
        tw[s + 0] = f00;
        tw[s + 1] = f01;
        tw[s + 2] = f10;
        tw[s + 3] = f11;
    }
    __syncthreads();

    auto issue_loads = [&](int kc, uint4 (&q)[2][4], float4 (&fw)[2]) {
#pragma unroll
        for (int it = 0; it < NIT; ++it) {
            int e = it * 256 + tid;
            int p = e / NCC, cc = e % NCC;
            int s = (p * 9 + kc) * 4;
            int4 bi = *(const int4*)&tb[s];
            fw[it] = *(const float4*)&tw[s];
            q[it][0] = *(const uint4*)(xh + (size_t)bi.x + cc * 8);
            q[it][1] = *(const uint4*)(xh + (size_t)bi.y + cc * 8);
            q[it][2] = *(const uint4*)(xh + (size_t)bi.z + cc * 8);
            q[it][3] = *(const uint4*)(xh + (size_t)bi.w + cc * 8);
        }
    };
    auto interp_write = [&](ushort* dst, uint4 (&q)[2][4], float4 (&fw)[2]) {
#pragma unroll
        for (int it = 0; it < NIT; ++it) {
            int e = it * 256 + tid;
            int p = e / NCC, cc = e % NCC;
            unsigned a0[4] = {q[it][0].x, q[it][0].y, q[it][0].z, q[it][0].w};
            unsigned a1[4] = {q[it][1].x, q[it][1].y, q[it][1].z, q[it][1].w};
            unsigned a2[4] = {q[it][2].x, q[it][2].y, q[it][2].z, q[it][2].w};
            unsigned a3[4] = {q[it][3].x, q[it][3].y, q[it][3].z, q[it][3].w};
            unsigned ov[4];
#pragma unroll
            for (int dw = 0; dw < 4; ++dw) {
                f32x2 v = unpk(a0[dw]) * fw[it].x;
                v += unpk(a1[dw]) * fw[it].y;
                v += unpk(a2[dw]) * fw[it].z;
                v += unpk(a3[dw]) * fw[it].w;
                ov[dw] = f2bf2(v.x, v.y);
            }
            *(uint4*)&dst[p * AST + cc * 8] = uint4{ov[0], ov[1], ov[2], ov[3]};
        }
    };

    {
        uint4 q[2][4];
        float4 fw[2];
        issue_loads(0, q, fw);
        interp_write(abuf0, q, fw);
    }
    __syncthreads();

    const int lane = tid & 63, wv = tid >> 6;
    const int n16 = lane & 15, quad = lane >> 4;

    f32x4 acc[2][2];
#pragma unroll
    for (int mt = 0; mt < 2; ++mt)
#pragma unroll
        for (int nt = 0; nt < 2; ++nt) acc[mt][nt] = (f32x4){0.f, 0.f, 0.f, 0.f};

    const ushort* bbase[2];
#pragma unroll
    for (int nt = 0; nt < 2; ++nt)
        bbase[nt] = wt + (size_t)(wv * 32 + nt * 16 + n16) * KP + quad * 8;

#pragma unroll 1
    for (int kc = 0; kc < 9; ++kc) {
        uint4 q[2][4];
        float4 fw[2];
        if (kc < 8) issue_loads(kc + 1, q, fw);

        const ushort* ab = (kc & 1) ? abuf1 : abuf0;
#pragma unroll
        for (int s = 0; s < C / 32; ++s) {
            short8 av[2], bv[2];
#pragma unroll
            for (int mt = 0; mt < 2; ++mt)
                av[mt] = *(const short8*)(ab + (mt * 16 + n16) * AST + s * 32 +
                                          quad * 8);
#pragma unroll
            for (int nt = 0; nt < 2; ++nt)
                bv[nt] = *(const short8*)(bbase[nt] + kc * CPW + s * 32);
#pragma unroll
            for (int mt = 0; mt < 2; ++mt)
#pragma unroll
                for (int nt = 0; nt < 2; ++nt)
                    acc[mt][nt] = __builtin_amdgcn_mfma_f32_16x16x32_bf16(
                        av[mt], bv[nt], acc[mt][nt], 0, 0, 0);
        }
        if (kc < 8)
            interp_write((kc & 1) ? abuf0 : abuf1, q, fw);
        __syncthreads();
    }

    // ---- epilogue: transpose via LDS; stores + fused bn partial stats ----
    float* sm = (float*)smem_raw;
    constexpr int SROW = PIX + 1;
#pragma unroll
    for (int mt = 0; mt < 2; ++mt)
#pragma unroll
        for (int nt = 0; nt < 2; ++nt) {
            int o = wv * 32 + nt * 16 + n16;
            int mb = mt * 16 + quad * 4;
#pragma unroll
            for (int r = 0; r < 4; ++r) sm[o * SROW + mb + r] = acc[mt][nt][r];
        }
    __syncthreads();
    {
        int o = tid >> 1, half = tid & 1;
        constexpr int HP = PIX / 2;
        const float* sp = sm + o * SROW + half * HP;
        float* op = out + (((size_t)(b * 128 + o)) << 14) + hw0 + half * HP;
        float s = 0.f, qq = 0.f;
#pragma unroll
        for (int i = 0; i < HP; i += 4) {
            float4 v = make_float4(sp[i], sp[i + 1], sp[i + 2], sp[i + 3]);
            *(float4*)(op + i) = v;
            s += v.x + v.y + v.z + v.w;
            qq += v.x * v.x + v.y * v.y + v.z * v.z + v.w * v.w;
        }
        s += __shfl_down(s, 1, 64);
        qq += __shfl_down(qq, 1, 64);
        if (half == 0) {
            float* pr = praw + (blockIdx.x & 7) * 256;
            atomicAdd(&pr[o], s);
            atomicAdd(&pr[128 + o], qq);
        }
    }
}

// ---- deformable conv stage-2: block = 16 cols x 2 rows -> block-local
// 2x2 maxpool. Writes only pooled raw max (NCHW 64x64) + bn stats. ----
template <int C>
__global__ __launch_bounds__(256) void deform_mfma3p(
    const ushort* __restrict__ xh, const float* __restrict__ dyb,
    const float* __restrict__ dxb, const float* __restrict__ mob,
    const ushort* __restrict__ wt, float* __restrict__ pout,
    float* __restrict__ praw) {
    constexpr int PIX = 32;
    constexpr int AST = C + 8;
    constexpr int CPW = C + 8;
    constexpr int KP = ((9 * CPW + 31) / 32) * 32;
    constexpr int NCC = C / 8;
    constexpr int NIT = PIX * NCC / 256;
    constexpr int ABUF = PIX * AST;

    __shared__ __align__(16) char smem_raw[2 * ABUF * 2 + PIX * 9 * 32];
    ushort* abuf0 = (ushort*)smem_raw;
    ushort* abuf1 = abuf0 + ABUF;
    int* tb = (int*)(abuf0 + 2 * ABUF);
    float* tw = (float*)(tb + PIX * 9 * 4);

    // bid = b*512 + rp*8 + g : rp = row pair (0..63), g = col group (0..7)
    const int bid = blockIdx.x;
    const int b = bid >> 9;
    const int rp = (bid >> 3) & 63;
    const int g = bid & 7;
    const int tid = threadIdx.x;

    // pixel p in [0,32): row = 2*rp + (p>>4), col = g*16 + (p&15)
    for (int r = tid; r < PIX * 9; r += 256) {
        int p = r & (PIX - 1), k = r / PIX;
        int row = 2 * rp + (p >> 4), col = g * 16 + (p & 15);
        int oi = ((b * 9 + k) << 14) + (row << 7) + col;
        float py = (float)(row + k / 3 - 1) + dyb[oi];
        float px = (float)(col + k % 3 - 1) + dxb[oi];
        float mv = mob[oi];
        float y0f = floorf(py), x0f = floorf(px);
        float wy = py - y0f, wx = px - x0f;
        int y0 = (int)y0f, x0 = (int)x0f;
        int y1 = y0 + 1, x1 = x0 + 1;
        float f00 = (1.f - wy) * (1.f - wx) *
                    (((unsigned)y0 < 128u && (unsigned)x0 < 128u) ? mv : 0.f);
        float f01 = (1.f - wy) * wx *
                    (((unsigned)y0 < 128u && (unsigned)x1 < 128u) ? mv : 0.f);
        float f10 = wy * (1.f - wx) *
                    (((unsigned)y1 < 128u && (unsigned)x0 < 128u) ? mv : 0.f);
        float f11 = wy * wx *
                    (((unsigned)y1 < 128u && (unsigned)x1 < 128u) ? mv : 0.f);
        int cy0 = min(max(y0, 0), 127), cy1 = min(max(y1, 0), 127);
        int cx0 = min(max(x0, 0), 127), cx1 = min(max(x1, 0), 127);
        int bpx = b << 14;
        int s = (p * 9 + k) * 4;
        tb[s + 0] = (bpx + (cy0 << 7) + cx0) * C;
        tb[s + 1] = (bpx + (cy0 << 7) + cx1) * C;
        tb[s + 2] = (bpx + (cy1 << 7) + cx0) * C;
        tb[s + 3] = (bpx + (cy1 << 7) + cx1) * C;
        tw[s + 0] = f00;
        tw[s + 1] = f01;
        tw[s + 2] = f10;
        tw[s + 3] = f11;
    }
    __syncthreads();

    auto issue_loads = [&](int kc, uint4 (&q)[2][4], float4 (&fw)[2]) {
#pragma unroll
        for (int it = 0; it < NIT; ++it) {
            int e = it * 256 + tid;
            int p = e / NCC, cc = e % NCC;
            int s = (p * 9 + kc) * 4;
            int4 bi = *(const int4*)&tb[s];
            fw[it] = *(const float4*)&tw[s];
            q[it][0] = *(const uint4*)(xh + (size_t)bi.x + cc * 8);
            q[it][1] = *(const uint4*)(xh + (size_t)bi.y + cc * 8);
            q[it][2] = *(const uint4*)(xh + (size_t)bi.z + cc * 8);
            q[it][3] = *(const uint4*)(xh + (size_t)bi.w + cc * 8);
        }
    };
    auto interp_write = [&](ushort* dst, uint4 (&q)[2][4], float4 (&fw)[2]) {
#pragma unroll
        for (int it = 0; it < NIT; ++it) {
            int e = it * 256 + tid;
            int p = e / NCC, cc = e % NCC;
            unsigned a0[4] = {q[it][0].x, q[it][0].y, q[it][0].z, q[it][0].w};
            unsigned a1[4] = {q[it][1].x, q[it][1].y, q[it][1].z, q[it][1].w};
            unsigned a2[4] = {q[it][2].x, q[it][2].y, q[it][2].z, q[it][2].w};
            unsigned a3[4] = {q[it][3].x, q[it][3].y, q[it][3].z, q[it][3].w};
            unsigned ov[4];
#pragma unroll
            for (int dw = 0; dw < 4; ++dw) {
                f32x2 v = unpk(a0[dw]) * fw[it].x;
                v += unpk(a1[dw]) * fw[it].y;
                v += unpk(a2[dw]) * fw[it].z;
                v += unpk(a3[dw]) * fw[it].w;
                ov[dw] = f2bf2(v.x, v.y);
            }
            *(uint4*)&dst[p * AST + cc * 8] = uint4{ov[0], ov[1], ov[2], ov[3]};
        }
    };

    {
        uint4 q[2][4];
        float4 fw[2];
        issue_loads(0, q, fw);
        interp_write(abuf0, q, fw);
    }
    __syncthreads();

    const int lane = tid & 63, wv = tid >> 6;
    const int n16 = lane & 15, quad = lane >> 4;

    f32x4 acc[2][2];
#pragma unroll
    for (int mt = 0; mt < 2; ++mt)
#pragma unroll
        for (int nt = 0; nt < 2; ++nt) acc[mt][nt] = (f32x4){0.f, 0.f, 0.f, 0.f};

    const ushort* bbase[2];
#pragma unroll
    for (int nt = 0; nt < 2; ++nt)
        bbase[nt] = wt + (size_t)(wv * 32 + nt * 16 + n16) * KP + quad * 8;

#pragma unroll 1
    for (int kc = 0; kc < 9; ++kc) {
        uint4 q[2][4];
        float4 fw[2];
        if (kc < 8) issue_loads(kc + 1, q, fw);

        const ushort* ab = (kc & 1) ? abuf1 : abuf0;
#pragma unroll
        for (int s = 0; s < C / 32; ++s) {
            short8 av[2], bv[2];
#pragma unroll
            for (int mt = 0; mt < 2; ++mt)
                av[mt] = *(const short8*)(ab + (mt * 16 + n16) * AST + s * 32 +
                                          quad * 8);
#pragma unroll
            for (int nt = 0; nt < 2; ++nt)
                bv[nt] = *(const short8*)(bbase[nt] + kc * CPW + s * 32);
#pragma unroll
            for (int mt = 0; mt < 2; ++mt)
#pragma unroll
                for (int nt = 0; nt < 2; ++nt)
                    acc[mt][nt] = __builtin_amdgcn_mfma_f32_16x16x32_bf16(
                        av[mt], bv[nt], acc[mt][nt], 0, 0, 0);
        }
        if (kc < 8)
            interp_write((kc & 1) ? abuf0 : abuf1, q, fw);
        __syncthreads();
    }

    // ---- epilogue: stats from full-res tile + block-local 2x2 pool ----
    float* sm = (float*)smem_raw;
    constexpr int SROW = PIX + 1;
#pragma unroll
    for (int mt = 0; mt < 2; ++mt)
#pragma unroll
        for (int nt = 0; nt < 2; ++nt) {
            int o = wv * 32 + nt * 16 + n16;
            int mb = mt * 16 + quad * 4;
#pragma unroll
            for (int r = 0; r < 4; ++r) sm[o * SROW + mb + r] = acc[mt][nt][r];
        }
    __syncthreads();
    {
        int o = tid >> 1, half = tid & 1;
        const float* so = sm + o * SROW;
        // stats over this thread's 16 pixels (half of the 32)
        const float* sp = so + half * 16;
        float s = 0.f, qq = 0.f;
#pragma unroll
        for (int i = 0; i < 16; i += 4) {
            float4 v = make_float4(sp[i], sp[i + 1], sp[i + 2], sp[i + 3]);
            s += v.x + v.y + v.z + v.w;
            qq += v.x * v.x + v.y * v.y + v.z * v.z + v.w * v.w;
        }
        s += __shfl_down(s, 1, 64);
        qq += __shfl_down(qq, 1, 64);
        if (half == 0) {
            float* pr = praw + (blockIdx.x & 7) * 256;
            atomicAdd(&pr[o], s);
            atomicAdd(&pr[128 + o], qq);
        }
        // pooled: pc = half*4 + i, max over p in {2pc,2pc+1,16+2pc,16+2pc+1}
        float4 pv;
#pragma unroll
        for (int i = 0; i < 4; ++i) {
            int pc = half * 4 + i;
            float m0v = fmaxf(so[2 * pc], so[2 * pc + 1]);
            float m1v = fmaxf(so[16 + 2 * pc], so[16 + 2 * pc + 1]);
            ((float*)&pv)[i] = fmaxf(m0v, m1v);
        }
        // pout NCHW pooled: ((b*128+o)*4096) + rp*64 + g*8 + half*4
        *(float4*)(pout + (((size_t)(b * 128 + o)) << 12) + rp * 64 + g * 8 +
                   half * 4) = pv;
    }
}

// ---- pooled normalize: out = relu((pout - mean) * rstd) ----
__global__ __launch_bounds__(256) void pool_norm(const float* __restrict__ pout,
                                                 const float* __restrict__ praw,
                                                 float* __restrict__ out) {
    __shared__ float lstats[256];
    if (threadIdx.x < 128) {
        int c = threadIdx.x;
        float s = 0.f, q = 0.f;
#pragma unroll
        for (int r = 0; r < 8; ++r) {
            s += praw[r * 256 + c];
            q += praw[r * 256 + 128 + c];
        }
        float mean = s / 65536.f;
        float var = q / 65536.f - mean * mean;
        lstats[c] = mean;
        lstats[128 + c] = rsqrtf(var + 1e-5f);
    }
    __syncthreads();
    int i = blockIdx.x * 256 + threadIdx.x;  // float4 index, total 524288
    int c = (i >> 10) & 127;                 // (i*4 >> 12) & 127
    float mean = lstats[c], rstd = lstats[128 + c];
    float4 v = ((const float4*)pout)[i];
    v.x = fmaxf(0.f, (v.x - mean) * rstd);
    v.y = fmaxf(0.f, (v.y - mean) * rstd);
    v.z = fmaxf(0.f, (v.z - mean) * rstd);
    v.w = fmaxf(0.f, (v.w - mean) * rstd);
    ((float4*)out)[i] = v;
}

extern "C" void kernel_launch(void* const* d_in, const int* in_sizes, int n_in,
                              void* d_out, int out_size, void* d_ws,
                              size_t ws_size, hipStream_t stream) {
    (void)in_sizes;
    (void)n_in;
    (void)out_size;
    (void)ws_size;
    const float* x = (const float*)d_in[0];
    const float* w_off1 = (const float*)d_in[1];
    const float* b_off1 = (const float*)d_in[2];
    const float* w_mod1 = (const float*)d_in[3];
    const float* b_mod1 = (const float*)d_in[4];
    const float* w1 = (const float*)d_in[5];
    const float* w_off2 = (const float*)d_in[6];
    const float* b_off2 = (const float*)d_in[7];
    const float* w_mod2 = (const float*)d_in[8];
    const float* b_mod2 = (const float*)d_in[9];
    const float* w2 = (const float*)d_in[10];
    float* out = (float*)d_out;
    float* ws = (float*)d_ws;

    // KP1 = 672 (C=64, CP=72), KP2 = 1248 (C=128, CP=136)
    ushort* Wt1 = (ushort*)ws;                            // 86016 ush = 43008 f
    ushort* Wt2 = (ushort*)(ws + 43008);                  // 159744 ush = 79872 f
    ushort* Wo1 = (ushort*)(ws + 43008 + 79872);          // need 18432 ush
    ushort* Wo2 = (ushort*)(ws + 43008 + 79872 + 16384);  // need 36864 ush
    float* dyb = ws + 172032;
    float* dxb = dyb + 589824;
    float* mob = dxb + 589824;
    float* hbuf = mob + 589824;      // 8388608 f: h1 fp32; later pout (2M f)
    float* xhf = hbuf + 8388608;     // 2097152 f: x as NHWC bf16
    float* h1hf = xhf + 2097152;     // 4194304 f: h1 as NHWC bf16
    float* praw = h1hf + 4194304;    // 2048 (8 replicas x 256)
    ushort* xh = (ushort*)xhf;
    ushort* h1h = (ushort*)h1hf;

    prep_weights<<<1176, 256, 0, stream>>>(w1, w2, w_off1, w_mod1, w_off2,
                                           w_mod2, Wt1, Wt2, Wo1, Wo2);

    // ---- stage 1 ----
    nhwc_cvt<64><<<1024, 256, 0, stream>>>(x, (unsigned*)xh);
    offmod_nhwc<64><<<1024, 256, 0, stream>>>(xh, Wo1, b_off1, b_mod1, dyb, dxb,
                                              mob, praw);
    deform_mfma3<64><<<2048, 256, 0, stream>>>(xh, dyb, dxb, mob, Wt1, hbuf,
                                               praw);
    bn_apply_cvt<128><<<1024, 256, 0, stream>>>(hbuf, praw, (unsigned*)h1h);

    // ---- stage 2 ----
    offmod_nhwc<128><<<1024, 256, 0, stream>>>(h1h, Wo2, b_off2, b_mod2, dyb,
                                               dxb, mob, praw);
    // hbuf (h1 fp32) is dead after bn_apply_cvt: reuse for pooled raw max
    deform_mfma3p<128><<<2048, 256, 0, stream>>>(h1h, dyb, dxb, mob, Wt2, hbuf,
                                                 praw);
    pool_norm<<<2048, 256, 0, stream>>>(hbuf, praw, out);
}

// Round 17
// 280.523 us; speedup vs baseline: 1.1019x; 1.0257x over previous
//
#include <hip/hip_runtime.h>
#include <math.h>

#define HH 128
#define WW 128
#define HWSZ 16384

typedef __attribute__((ext_vector_type(8))) short short8;
typedef __attribute__((ext_vector_type(4))) float f32x4;
typedef __attribute__((ext_vector_type(2))) float f32x2;
typedef unsigned short ushort;

__device__ __forceinline__ ushort f2bf(float f) {
    unsigned int u = __float_as_uint(f);
    unsigned int r = u + 0x7fffu + ((u >> 16) & 1u);
    return (ushort)(r >> 16);
}
// pack two floats -> packed bf16 dword (lo in [15:0], hi in [31:16]), RNE.
__device__ __forceinline__ unsigned f2bf2(float lo, float hi) {
#if __has_builtin(__builtin_amdgcn_cvt_pk_bf16_f32)
    auto r = __builtin_amdgcn_cvt_pk_bf16_f32(lo, hi);
    unsigned u;
    __builtin_memcpy(&u, &r, 4);
    return u;
#else
    return (unsigned)f2bf(lo) | ((unsigned)f2bf(hi) << 16);
#endif
}
// unpack 2 packed bf16 (one dword) to float2: .x = low half, .y = high half
__device__ __forceinline__ f32x2 unpk(unsigned u) {
    return (f32x2){__uint_as_float(u << 16),
                   __uint_as_float(u & 0xffff0000u)};
}

// ---- merged weight prep: wpad1 | wpad2 | woff1 | woff2 in one launch ----
__global__ __launch_bounds__(256) void prep_weights(
    const float* __restrict__ w1, const float* __restrict__ w2,
    const float* __restrict__ w_off1, const float* __restrict__ w_mod1,
    const float* __restrict__ w_off2, const float* __restrict__ w_mod2,
    ushort* __restrict__ Wt1, ushort* __restrict__ Wt2,
    ushort* __restrict__ Wo1, ushort* __restrict__ Wo2) {
    int bid = blockIdx.x, tid = threadIdx.x;
    if (bid < 336) {
        int i = bid * 256 + tid;
        int o = i / 672, kq = i % 672;
        int k = kq / 72, c = kq % 72;
        float v = (k < 9 && c < 64) ? w1[(o * 64 + c) * 9 + k] : 0.f;
        Wt1[i] = f2bf(v);
    } else if (bid < 960) {
        int i = (bid - 336) * 256 + tid;
        int o = i / 1248, kq = i % 1248;
        int k = kq / 136, c = kq % 136;
        float v = (k < 9 && c < 128) ? w2[(o * 128 + c) * 9 + k] : 0.f;
        Wt2[i] = f2bf(v);
    } else if (bid < 1032) {
        int i = (bid - 960) * 256 + tid;  // < 32*576
        int o = i / 576, kap = i % 576;
        int k = kap / 64, c = kap % 64;
        float v = 0.f;
        if (o < 18) v = w_off1[(o * 64 + c) * 9 + k];
        else if (o < 27) v = w_mod1[((o - 18) * 64 + c) * 9 + k];
        Wo1[i] = f2bf(v);
    } else {
        int i = (bid - 1032) * 256 + tid;  // < 32*1152
        int o = i / 1152, kap = i % 1152;
        int k = kap / 128, c = kap % 128;
        float v = 0.f;
        if (o < 18) v = w_off2[(o * 128 + c) * 9 + k];
        else if (o < 27) v = w_mod2[((o - 18) * 128 + c) * 9 + k];
        Wo2[i] = f2bf(v);
    }
}

// ---- NCHW fp32 -> NHWC bf16 converter (tiled transpose) ----
template <int C>
__global__ __launch_bounds__(256) void nhwc_cvt(const float* __restrict__ xin,
                                                unsigned* __restrict__ xout) {
    __shared__ float tile[64][C + 1];
    const int m0 = blockIdx.x * 64;
    const int b = m0 >> 14;
    const int hw0 = m0 & 16383;
    const int t = threadIdx.x;
    const int pr = t & 63, cr = t >> 6;
#pragma unroll
    for (int it = 0; it < C / 4; ++it) {
        int c = it * 4 + cr;
        tile[pr][c] = xin[(((size_t)(b * C + c)) << 14) + hw0 + pr];
    }
    __syncthreads();
    constexpr int CH = C / 2;
#pragma unroll
    for (int it = 0; it < 64 * CH / 256; ++it) {
        int slot = it * 256 + t;
        int p = slot / CH, cc = slot % CH;
        xout[(size_t)(m0 + p) * CH + cc] =
            f2bf2(tile[p][2 * cc], tile[p][2 * cc + 1]);
    }
}

// ---- elementwise bn finalize + norm/relu on raw NHWC bf16 ----
__global__ __launch_bounds__(256) void bn_apply_ew(
    const unsigned* __restrict__ xin, const float* __restrict__ praw,
    unsigned* __restrict__ xout) {
    __shared__ float lstats[256];
    if (threadIdx.x < 128) {
        int c = threadIdx.x;
        float s = 0.f, q = 0.f;
#pragma unroll
        for (int r = 0; r < 8; ++r) {
            s += praw[r * 256 + c];
            q += praw[r * 256 + 128 + c];
        }
        float mean = s / 65536.f;
        float var = q / 65536.f - mean * mean;
        lstats[c] = mean;
        lstats[128 + c] = rsqrtf(var + 1e-5f);
    }
    __syncthreads();
    int i = blockIdx.x * 256 + threadIdx.x;  // uint4 index (4 dwords = 8 ch)
    uint4 v = ((const uint4*)xin)[i];
    int c0 = ((i * 4) & 63) * 2;  // 64 dwords per pixel (128 ch)
    unsigned ov[4];
    unsigned in[4] = {v.x, v.y, v.z, v.w};
#pragma unroll
    for (int d = 0; d < 4; ++d) {
        int c = c0 + 2 * d;
        f32x2 f = unpk(in[d]);
        float a = fmaxf(0.f, (f.x - lstats[c]) * lstats[128 + c]);
        float b2 = fmaxf(0.f, (f.y - lstats[c + 1]) * lstats[128 + c + 1]);
        ov[d] = f2bf2(a, b2);
    }
    ((uint4*)xout)[i] = uint4{ov[0], ov[1], ov[2], ov[3]};
}

// ---- offset/mod conv: NHWC-bf16 direct A-fragment MFMA GEMM ----
// also zeroes the bn praw replicas (blocks 0..7) for the following deform.
template <int C>
__global__ __launch_bounds__(256) void offmod_nhwc(
    const ushort* __restrict__ xh, const ushort* __restrict__ wt,
    const float* __restrict__ b_off, const float* __restrict__ b_mod,
    float* __restrict__ dyb, float* __restrict__ dxb, float* __restrict__ mob,
    float* __restrict__ praw) {
    constexpr int K = C * 9;
    if (blockIdx.x < 8) praw[blockIdx.x * 256 + threadIdx.x] = 0.f;
    const int m0 = blockIdx.x * 64;
    const int b = m0 >> 14;
    const int hw0 = m0 & 16383;
    const int h = hw0 >> 7;
    const int w0 = hw0 & 127;
    const int tid = threadIdx.x;
    const int lane = tid & 63, wv = tid >> 6;
    const int n16 = lane & 15, quad = lane >> 4;
    const int p = wv * 16 + n16;
    const int w = w0 + p;

    int tbase[9];
    bool tval[9];
#pragma unroll
    for (int k = 0; k < 9; ++k) {
        int yy = h + k / 3 - 1, xx = w + k % 3 - 1;
        tval[k] = ((unsigned)yy < 128u) && ((unsigned)xx < 128u);
        int cy = min(max(yy, 0), 127), cx = min(max(xx, 0), 127);
        tbase[k] = ((b << 14) + (cy << 7) + cx) * C + quad * 8;
    }

    f32x4 acc[2];
    acc[0] = (f32x4){0.f, 0.f, 0.f, 0.f};
    acc[1] = (f32x4){0.f, 0.f, 0.f, 0.f};

    const ushort* b0p = wt + (size_t)n16 * K + quad * 8;
    const ushort* b1p = wt + (size_t)(16 + n16) * K + quad * 8;

#pragma unroll
    for (int s = 0; s < K / 32; ++s) {
        const int k = (s * 32) / C;
        const int c0 = (s * 32) % C;
        short8 a = (short8){0, 0, 0, 0, 0, 0, 0, 0};
        if (tval[k]) a = *(const short8*)(xh + (size_t)tbase[k] + c0);
        const short8 bv0 = *(const short8*)(b0p + s * 32);
        const short8 bv1 = *(const short8*)(b1p + s * 32);
        acc[0] = __builtin_amdgcn_mfma_f32_16x16x32_bf16(a, bv0, acc[0], 0, 0, 0);
        acc[1] = __builtin_amdgcn_mfma_f32_16x16x32_bf16(a, bv1, acc[1], 0, 0, 0);
    }

    __shared__ float sm[32 * 65];
#pragma unroll
    for (int nt = 0; nt < 2; ++nt) {
        int n = nt * 16 + n16;
        int pb = wv * 16 + quad * 4;
#pragma unroll
        for (int r = 0; r < 4; ++r) sm[n * 65 + pb + r] = acc[nt][r];
    }
    __syncthreads();
    {
        int n = tid >> 3, i8 = tid & 7;
        if (n < 27) {
            const float* sp = sm + n * 65 + i8 * 8;
            int px = hw0 + i8 * 8;
            if (n < 18) {
                int k = n >> 1;
                float bias = b_off[n];
                float* dst =
                    ((n & 1) ? dxb : dyb) + (((size_t)(b * 9 + k)) << 14) + px;
#pragma unroll
                for (int j = 0; j < 8; j += 4) {
                    float4 v = make_float4(sp[j] + bias, sp[j + 1] + bias,
                                           sp[j + 2] + bias, sp[j + 3] + bias);
                    *(float4*)(dst + j) = v;
                }
            } else {
                float bias = b_mod[n - 18];
                float* dst = mob + (((size_t)(b * 9 + (n - 18))) << 14) + px;
#pragma unroll
                for (int j = 0; j < 8; j += 4) {
                    float4 v;
                    v.x = 2.f / (1.f + expf(-(sp[j] + bias)));
                    v.y = 2.f / (1.f + expf(-(sp[j + 1] + bias)));
                    v.z = 2.f / (1.f + expf(-(sp[j + 2] + bias)));
                    v.w = 2.f / (1.f + expf(-(sp[j + 3] + bias)));
                    *(float4*)(dst + j) = v;
                }
            }
        }
    }
}

// ---- deformable conv v3 (stage 1): K-chunked double-buffered GEMM ----
// + fused bn partial stats; writes RAW bf16 NHWC directly (consumer layout).
template <int C>
__global__ __launch_bounds__(256) void deform_mfma3(
    const ushort* __restrict__ xh, const float* __restrict__ dyb,
    const float* __restrict__ dxb, const float* __restrict__ mob,
    const ushort* __restrict__ wt, unsigned* __restrict__ xout,
    float* __restrict__ praw) {
    constexpr int PIX = 32;
    constexpr int AST = C + 8;
    constexpr int CPW = C + 8;
    constexpr int KP = ((9 * CPW + 31) / 32) * 32;
    constexpr int NCC = C / 8;
    constexpr int NIT = PIX * NCC / 256;
    constexpr int ABUF = PIX * AST;

    __shared__ __align__(16) char smem_raw[2 * ABUF * 2 + PIX * 9 * 32];
    ushort* abuf0 = (ushort*)smem_raw;
    ushort* abuf1 = abuf0 + ABUF;
    int* tb = (int*)(abuf0 + 2 * ABUF);
    float* tw = (float*)(tb + PIX * 9 * 4);

    const int m0 = blockIdx.x * PIX;
    const int b = m0 >> 14;
    const int hw0 = m0 & 16383;
    const int h = hw0 >> 7, w0 = hw0 & 127;
    const int tid = threadIdx.x;

    for (int r = tid; r < PIX * 9; r += 256) {
        int p = r & (PIX - 1), k = r / PIX;
        int oi = ((b * 9 + k) << 14) + hw0 + p;
        float py = (float)(h + k / 3 - 1) + dyb[oi];
        float px = (float)(w0 + p + k % 3 - 1) + dxb[oi];
        float mv = mob[oi];
        float y0f = floorf(py), x0f = floorf(px);
        float wy = py - y0f, wx = px - x0f;
        int y0 = (int)y0f, x0 = (int)x0f;
        int y1 = y0 + 1, x1 = x0 + 1;
        float f00 = (1.f - wy) * (1.f - wx) *
                    (((unsigned)y0 < 128u && (unsigned)x0 < 128u) ? mv : 0.f);
        float f01 = (1.f - wy) * wx *
                    (((unsigned)y0 < 128u && (unsigned)x1 < 128u) ? mv : 0.f);
        float f10 = wy * (1.f - wx) *
                    (((unsigned)y1 < 128u && (unsigned)x0 < 128u) ? mv : 0.f);
        float f11 = wy * wx *
                    (((unsigned)y1 < 128u && (unsigned)x1 < 128u) ? mv : 0.f);
        int cy0 = min(max(y0, 0), 127), cy1 = min(max(y1, 0), 127);
        int cx0 = min(max(x0, 0), 127), cx1 = min(max(x1, 0), 127);
        int bpx = b << 14;
        int s = (p * 9 + k) * 4;
        tb[s + 0] = (bpx + (cy0 << 7) + cx0) * C;
        tb[s + 1] = (bpx + (cy0 << 7) + cx1) * C;
        tb[s + 2] = (bpx + (cy1 << 7) + cx0) * C;
        tb[s + 3] = (bpx + (cy1 << 7) + cx1) * C;
        tw[s + 0] = f00;
        tw[s + 1] = f01;
        tw[s + 2] = f10;
        tw[s + 3] = f11;
    }
    __syncthreads();

    auto issue_loads = [&](int kc, uint4 (&q)[2][4], float4 (&fw)[2]) {
#pragma unroll
        for (int it = 0; it < NIT; ++it) {
            int e = it * 256 + tid;
            int p = e / NCC, cc = e % NCC;
            int s = (p * 9 + kc) * 4;
            int4 bi = *(const int4*)&tb[s];
            fw[it] = *(const float4*)&tw[s];
            q[it][0] = *(const uint4*)(xh + (size_t)bi.x + cc * 8);
            q[it][1] = *(const uint4*)(xh + (size_t)bi.y + cc * 8);
            q[it][2] = *(const uint4*)(xh + (size_t)bi.z + cc * 8);
            q[it][3] = *(const uint4*)(xh + (size_t)bi.w + cc * 8);
        }
    };
    auto interp_write = [&](ushort* dst, uint4 (&q)[2][4], float4 (&fw)[2]) {
#pragma unroll
        for (int it = 0; it < NIT; ++it) {
            int e = it * 256 + tid;
            int p = e / NCC, cc = e % NCC;
            unsigned a0[4] = {q[it][0].x, q[it][0].y, q[it][0].z, q[it][0].w};
            unsigned a1[4] = {q[it][1].x, q[it][1].y, q[it][1].z, q[it][1].w};
            unsigned a2[4] = {q[it][2].x, q[it][2].y, q[it][2].z, q[it][2].w};
            unsigned a3[4] = {q[it][3].x, q[it][3].y, q[it][3].z, q[it][3].w};
            unsigned ov[4];
#pragma unroll
            for (int dw = 0; dw < 4; ++dw) {
                f32x2 v = unpk(a0[dw]) * fw[it].x;
                v += unpk(a1[dw]) * fw[it].y;
                v += unpk(a2[dw]) * fw[it].z;
                v += unpk(a3[dw]) * fw[it].w;
                ov[dw] = f2bf2(v.x, v.y);
            }
            *(uint4*)&dst[p * AST + cc * 8] = uint4{ov[0], ov[1], ov[2], ov[3]};
        }
    };

    {
        uint4 q[2][4];
        float4 fw[2];
        issue_loads(0, q, fw);
        interp_write(abuf0, q, fw);
    }
    __syncthreads();

    const int lane = tid & 63, wv = tid >> 6;
    const int n16 = lane & 15, quad = lane >> 4;

    f32x4 acc[2][2];
#pragma unroll
    for (int mt = 0; mt < 2; ++mt)
#pragma unroll
        for (int nt = 0; nt < 2; ++nt) acc[mt][nt] = (f32x4){0.f, 0.f, 0.f, 0.f};

    const ushort* bbase[2];
#pragma unroll
    for (int nt = 0; nt < 2; ++nt)
        bbase[nt] = wt + (size_t)(wv * 32 + nt * 16 + n16) * KP + quad * 8;

#pragma unroll 1
    for (int kc = 0; kc < 9; ++kc) {
        uint4 q[2][4];
        float4 fw[2];
        if (kc < 8) issue_loads(kc + 1, q, fw);

        const ushort* ab = (kc & 1) ? abuf1 : abuf0;
#pragma unroll
        for (int s = 0; s < C / 32; ++s) {
            short8 av[2], bv[2];
#pragma unroll
            for (int mt = 0; mt < 2; ++mt)
                av[mt] = *(const short8*)(ab + (mt * 16 + n16) * AST + s * 32 +
                                          quad * 8);
#pragma unroll
            for (int nt = 0; nt < 2; ++nt)
                bv[nt] = *(const short8*)(bbase[nt] + kc * CPW + s * 32);
#pragma unroll
            for (int mt = 0; mt < 2; ++mt)
#pragma unroll
                for (int nt = 0; nt < 2; ++nt)
                    acc[mt][nt] = __builtin_amdgcn_mfma_f32_16x16x32_bf16(
                        av[mt], bv[nt], acc[mt][nt], 0, 0, 0);
        }
        if (kc < 8)
            interp_write((kc & 1) ? abuf0 : abuf1, q, fw);
        __syncthreads();
    }

    // ---- epilogue: transpose via LDS; bn stats (fp32) + raw bf16 NHWC out ----
    float* sm = (float*)smem_raw;
    constexpr int SROW = PIX + 1;
#pragma unroll
    for (int mt = 0; mt < 2; ++mt)
#pragma unroll
        for (int nt = 0; nt < 2; ++nt) {
            int o = wv * 32 + nt * 16 + n16;
            int mb = mt * 16 + quad * 4;
#pragma unroll
            for (int r = 0; r < 4; ++r) sm[o * SROW + mb + r] = acc[mt][nt][r];
        }
    __syncthreads();
    {
        // stats: thread = (o, half), 16 px each, fp32-accurate
        int o = tid >> 1, half = tid & 1;
        const float* sp = sm + o * SROW + half * 16;
        float s = 0.f, qq = 0.f;
#pragma unroll
        for (int i = 0; i < 16; i += 4) {
            float4 v = make_float4(sp[i], sp[i + 1], sp[i + 2], sp[i + 3]);
            s += v.x + v.y + v.z + v.w;
            qq += v.x * v.x + v.y * v.y + v.z * v.z + v.w * v.w;
        }
        s += __shfl_down(s, 1, 64);
        qq += __shfl_down(qq, 1, 64);
        if (half == 0) {
            float* pr = praw + (blockIdx.x & 7) * 256;
            atomicAdd(&pr[o], s);
            atomicAdd(&pr[128 + o], qq);
        }
    }
    {
        // NHWC bf16 raw write: thread = (p = tid>>3, cc8 = tid&7), 16 ch
        int p = tid >> 3, cc8 = tid & 7;
        unsigned ov[8];
#pragma unroll
        for (int j = 0; j < 8; ++j) {
            int c = cc8 * 16 + 2 * j;
            ov[j] = f2bf2(sm[c * SROW + p], sm[(c + 1) * SROW + p]);
        }
        uint4* dst = (uint4*)(xout + ((size_t)(m0 + p)) * 64 + cc8 * 8);
        dst[0] = uint4{ov[0], ov[1], ov[2], ov[3]};
        dst[1] = uint4{ov[4], ov[5], ov[6], ov[7]};
    }
}

// ---- deformable conv stage-2: block = 16 cols x 2 rows -> block-local
// 2x2 maxpool. Writes only pooled raw max (NCHW 64x64) + bn stats. ----
template <int C>
__global__ __launch_bounds__(256) void deform_mfma3p(
    const ushort* __restrict__ xh, const float* __restrict__ dyb,
    const float* __restrict__ dxb, const float* __restrict__ mob,
    const ushort* __restrict__ wt, float* __restrict__ pout,
    float* __restrict__ praw) {
    constexpr int PIX = 32;
    constexpr int AST = C + 8;
    constexpr int CPW = C + 8;
    constexpr int KP = ((9 * CPW + 31) / 32) * 32;
    constexpr int NCC = C / 8;
    constexpr int NIT = PIX * NCC / 256;
    constexpr int ABUF = PIX * AST;

    __shared__ __align__(16) char smem_raw[2 * ABUF * 2 + PIX * 9 * 32];
    ushort* abuf0 = (ushort*)smem_raw;
    ushort* abuf1 = abuf0 + ABUF;
    int* tb = (int*)(abuf0 + 2 * ABUF);
    float* tw = (float*)(tb + PIX * 9 * 4);

    // bid = b*512 + rp*8 + g : rp = row pair (0..63), g = col group (0..7)
    const int bid = blockIdx.x;
    const int b = bid >> 9;
    const int rp = (bid >> 3) & 63;
    const int g = bid & 7;
    const int tid = threadIdx.x;

    // pixel p in [0,32): row = 2*rp + (p>>4), col = g*16 + (p&15)
    for (int r = tid; r < PIX * 9; r += 256) {
        int p = r & (PIX - 1), k = r / PIX;
        int row = 2 * rp + (p >> 4), col = g * 16 + (p & 15);
        int oi = ((b * 9 + k) << 14) + (row << 7) + col;
        float py = (float)(row + k / 3 - 1) + dyb[oi];
        float px = (float)(col + k % 3 - 1) + dxb[oi];
        float mv = mob[oi];
        float y0f = floorf(py), x0f = floorf(px);
        float wy = py - y0f, wx = px - x0f;
        int y0 = (int)y0f, x0 = (int)x0f;
        int y1 = y0 + 1, x1 = x0 + 1;
        float f00 = (1.f - wy) * (1.f - wx) *
                    (((unsigned)y0 < 128u && (unsigned)x0 < 128u) ? mv : 0.f);
        float f01 = (1.f - wy) * wx *
                    (((unsigned)y0 < 128u && (unsigned)x1 < 128u) ? mv : 0.f);
        float f10 = wy * (1.f - wx) *
                    (((unsigned)y1 < 128u && (unsigned)x0 < 128u) ? mv : 0.f);
        float f11 = wy * wx *
                    (((unsigned)y1 < 128u && (unsigned)x1 < 128u) ? mv : 0.f);
        int cy0 = min(max(y0, 0), 127), cy1 = min(max(y1, 0), 127);
        int cx0 = min(max(x0, 0), 127), cx1 = min(max(x1, 0), 127);
        int bpx = b << 14;
        int s = (p * 9 + k) * 4;
        tb[s + 0] = (bpx + (cy0 << 7) + cx0) * C;
        tb[s + 1] = (bpx + (cy0 << 7) + cx1) * C;
        tb[s + 2] = (bpx + (cy1 << 7) + cx0) * C;
        tb[s + 3] = (bpx + (cy1 << 7) + cx1) * C;
        tw[s + 0] = f00;
        tw[s + 1] = f01;
        tw[s + 2] = f10;
        tw[s + 3] = f11;
    }
    __syncthreads();

    auto issue_loads = [&](int kc, uint4 (&q)[2][4], float4 (&fw)[2]) {
#pragma unroll
        for (int it = 0; it < NIT; ++it) {
            int e = it * 256 + tid;
            int p = e / NCC, cc = e % NCC;
            int s = (p * 9 + kc) * 4;
            int4 bi = *(const int4*)&tb[s];
            fw[it] = *(const float4*)&tw[s];
            q[it][0] = *(const uint4*)(xh + (size_t)bi.x + cc * 8);
            q[it][1] = *(const uint4*)(xh + (size_t)bi.y + cc * 8);
            q[it][2] = *(const uint4*)(xh + (size_t)bi.z + cc * 8);
            q[it][3] = *(const uint4*)(xh + (size_t)bi.w + cc * 8);
        }
    };
    auto interp_write = [&](ushort* dst, uint4 (&q)[2][4], float4 (&fw)[2]) {
#pragma unroll
        for (int it = 0; it < NIT; ++it) {
            int e = it * 256 + tid;
            int p = e / NCC, cc = e % NCC;
            unsigned a0[4] = {q[it][0].x, q[it][0].y, q[it][0].z, q[it][0].w};
            unsigned a1[4] = {q[it][1].x, q[it][1].y, q[it][1].z, q[it][1].w};
            unsigned a2[4] = {q[it][2].x, q[it][2].y, q[it][2].z, q[it][2].w};
            unsigned a3[4] = {q[it][3].x, q[it][3].y, q[it][3].z, q[it][3].w};
            unsigned ov[4];
#pragma unroll
            for (int dw = 0; dw < 4; ++dw) {
                f32x2 v = unpk(a0[dw]) * fw[it].x;
                v += unpk(a1[dw]) * fw[it].y;
                v += unpk(a2[dw]) * fw[it].z;
                v += unpk(a3[dw]) * fw[it].w;
                ov[dw] = f2bf2(v.x, v.y);
            }
            *(uint4*)&dst[p * AST + cc * 8] = uint4{ov[0], ov[1], ov[2], ov[3]};
        }
    };

    {
        uint4 q[2][4];
        float4 fw[2];
        issue_loads(0, q, fw);
        interp_write(abuf0, q, fw);
    }
    __syncthreads();

    const int lane = tid & 63, wv = tid >> 6;
    const int n16 = lane & 15, quad = lane >> 4;

    f32x4 acc[2][2];
#pragma unroll
    for (int mt = 0; mt < 2; ++mt)
#pragma unroll
        for (int nt = 0; nt < 2; ++nt) acc[mt][nt] = (f32x4){0.f, 0.f, 0.f, 0.f};

    const ushort* bbase[2];
#pragma unroll
    for (int nt = 0; nt < 2; ++nt)
        bbase[nt] = wt + (size_t)(wv * 32 + nt * 16 + n16) * KP + quad * 8;

#pragma unroll 1
    for (int kc = 0; kc < 9; ++kc) {
        uint4 q[2][4];
        float4 fw[2];
        if (kc < 8) issue_loads(kc + 1, q, fw);

        const ushort* ab = (kc & 1) ? abuf1 : abuf0;
#pragma unroll
        for (int s = 0; s < C / 32; ++s) {
            short8 av[2], bv[2];
#pragma unroll
            for (int mt = 0; mt < 2; ++mt)
                av[mt] = *(const short8*)(ab + (mt * 16 + n16) * AST + s * 32 +
                                          quad * 8);
#pragma unroll
            for (int nt = 0; nt < 2; ++nt)
                bv[nt] = *(const short8*)(bbase[nt] + kc * CPW + s * 32);
#pragma unroll
            for (int mt = 0; mt < 2; ++mt)
#pragma unroll
                for (int nt = 0; nt < 2; ++nt)
                    acc[mt][nt] = __builtin_amdgcn_mfma_f32_16x16x32_bf16(
                        av[mt], bv[nt], acc[mt][nt], 0, 0, 0);
        }
        if (kc < 8)
            interp_write((kc & 1) ? abuf0 : abuf1, q, fw);
        __syncthreads();
    }

    // ---- epilogue: stats from full-res tile + block-local 2x2 pool ----
    float* sm = (float*)smem_raw;
    constexpr int SROW = PIX + 1;
#pragma unroll
    for (int mt = 0; mt < 2; ++mt)
#pragma unroll
        for (int nt = 0; nt < 2; ++nt) {
            int o = wv * 32 + nt * 16 + n16;
            int mb = mt * 16 + quad * 4;
#pragma unroll
            for (int r = 0; r < 4; ++r) sm[o * SROW + mb + r] = acc[mt][nt][r];
        }
    __syncthreads();
    {
        int o = tid >> 1, half = tid & 1;
        const float* so = sm + o * SROW;
        const float* sp = so + half * 16;
        float s = 0.f, qq = 0.f;
#pragma unroll
        for (int i = 0; i < 16; i += 4) {
            float4 v = make_float4(sp[i], sp[i + 1], sp[i + 2], sp[i + 3]);
            s += v.x + v.y + v.z + v.w;
            qq += v.x * v.x + v.y * v.y + v.z * v.z + v.w * v.w;
        }
        s += __shfl_down(s, 1, 64);
        qq += __shfl_down(qq, 1, 64);
        if (half == 0) {
            float* pr = praw + (blockIdx.x & 7) * 256;
            atomicAdd(&pr[o], s);
            atomicAdd(&pr[128 + o], qq);
        }
        float4 pv;
#pragma unroll
        for (int i = 0; i < 4; ++i) {
            int pc = half * 4 + i;
            float m0v = fmaxf(so[2 * pc], so[2 * pc + 1]);
            float m1v = fmaxf(so[16 + 2 * pc], so[16 + 2 * pc + 1]);
            ((float*)&pv)[i] = fmaxf(m0v, m1v);
        }
        *(float4*)(pout + (((size_t)(b * 128 + o)) << 12) + rp * 64 + g * 8 +
                   half * 4) = pv;
    }
}

// ---- pooled normalize: out = relu((pout - mean) * rstd) ----
__global__ __launch_bounds__(256) void pool_norm(const float* __restrict__ pout,
                                                 const float* __restrict__ praw,
                                                 float* __restrict__ out) {
    __shared__ float lstats[256];
    if (threadIdx.x < 128) {
        int c = threadIdx.x;
        float s = 0.f, q = 0.f;
#pragma unroll
        for (int r = 0; r < 8; ++r) {
            s += praw[r * 256 + c];
            q += praw[r * 256 + 128 + c];
        }
        float mean = s / 65536.f;
        float var = q / 65536.f - mean * mean;
        lstats[c] = mean;
        lstats[128 + c] = rsqrtf(var + 1e-5f);
    }
    __syncthreads();
    int i = blockIdx.x * 256 + threadIdx.x;  // float4 index, total 524288
    int c = (i >> 10) & 127;
    float mean = lstats[c], rstd = lstats[128 + c];
    float4 v = ((const float4*)pout)[i];
    v.x = fmaxf(0.f, (v.x - mean) * rstd);
    v.y = fmaxf(0.f, (v.y - mean) * rstd);
    v.z = fmaxf(0.f, (v.z - mean) * rstd);
    v.w = fmaxf(0.f, (v.w - mean) * rstd);
    ((float4*)out)[i] = v;
}

extern "C" void kernel_launch(void* const* d_in, const int* in_sizes, int n_in,
                              void* d_out, int out_size, void* d_ws,
                              size_t ws_size, hipStream_t stream) {
    (void)in_sizes;
    (void)n_in;
    (void)out_size;
    (void)ws_size;
    const float* x = (const float*)d_in[0];
    const float* w_off1 = (const float*)d_in[1];
    const float* b_off1 = (const float*)d_in[2];
    const float* w_mod1 = (const float*)d_in[3];
    const float* b_mod1 = (const float*)d_in[4];
    const float* w1 = (const float*)d_in[5];
    const float* w_off2 = (const float*)d_in[6];
    const float* b_off2 = (const float*)d_in[7];
    const float* w_mod2 = (const float*)d_in[8];
    const float* b_mod2 = (const float*)d_in[9];
    const float* w2 = (const float*)d_in[10];
    float* out = (float*)d_out;
    float* ws = (float*)d_ws;

    // KP1 = 672 (C=64, CP=72), KP2 = 1248 (C=128, CP=136)
    ushort* Wt1 = (ushort*)ws;                            // 86016 ush = 43008 f
    ushort* Wt2 = (ushort*)(ws + 43008);                  // 159744 ush = 79872 f
    ushort* Wo1 = (ushort*)(ws + 43008 + 79872);          // need 18432 ush
    ushort* Wo2 = (ushort*)(ws + 43008 + 79872 + 16384);  // need 36864 ush
    float* dyb = ws + 172032;
    float* dxb = dyb + 589824;
    float* mob = dxb + 589824;
    float* hbuf = mob + 589824;      // h1 raw bf16 NHWC (4M f); later pout (2M f)
    float* xhf = hbuf + 8388608;     // 2097152 f: x as NHWC bf16
    float* h1hf = xhf + 2097152;     // 4194304 f: h1 normalized NHWC bf16
    float* praw = h1hf + 4194304;    // 2048 (8 replicas x 256)
    ushort* xh = (ushort*)xhf;
    ushort* h1h = (ushort*)h1hf;

    prep_weights<<<1176, 256, 0, stream>>>(w1, w2, w_off1, w_mod1, w_off2,
                                           w_mod2, Wt1, Wt2, Wo1, Wo2);

    // ---- stage 1 ----
    nhwc_cvt<64><<<1024, 256, 0, stream>>>(x, (unsigned*)xh);
    offmod_nhwc<64><<<1024, 256, 0, stream>>>(xh, Wo1, b_off1, b_mod1, dyb, dxb,
                                              mob, praw);
    deform_mfma3<64><<<2048, 256, 0, stream>>>(xh, dyb, dxb, mob, Wt1,
                                               (unsigned*)hbuf, praw);
    bn_apply_ew<<<4096, 256, 0, stream>>>((const unsigned*)hbuf, praw,
                                          (unsigned*)h1h);

    // ---- stage 2 ----
    offmod_nhwc<128><<<1024, 256, 0, stream>>>(h1h, Wo2, b_off2, b_mod2, dyb,
                                               dxb, mob, praw);
    // hbuf (h1 raw) is dead after bn_apply_ew: reuse for pooled raw max
    deform_mfma3p<128><<<2048, 256, 0, stream>>>(h1h, dyb, dxb, mob, Wt2, hbuf,
                                                 praw);
    pool_norm<<<2048, 256, 0, stream>>>(hbuf, praw, out);
}